// Round 1
// baseline (1915.814 us; speedup 1.0000x reference)
//
#include <hip/hip_runtime.h>
#include <cmath>
#include <cstring>
#include <vector>

// ============================================================================
// Spherical CNN (s2conv -> 4x so3conv -> integrate -> MLP), MI355X gfx950.
// Round 1: correctness-first, fused per-slab ifft2+relu+fft2, fp32 everywhere.
// ============================================================================

#define DPI 3.14159265358979323846

// ---------------- compile-time sizes ----------------
static constexpr int OQh(int l) { return l*(4*l*l - 1)/3; }   // sum_{l'<l} (2l'+1)^2
static_assert(OQh(30) == 35990, "oq30");
static_assert(OQh(17) == 6545,  "oq17");
static_assert(OQh(9)  == 969,   "oq9");
static_assert(OQh(5)  == 165,   "oq5");
static_assert(OQh(3)  == 35,    "oq3");

// ---------------- workspace layout (bytes; every size is 16B-aligned) -------
static constexpr size_t WS_XF1 = 0;
static constexpr size_t WS_XH1 = WS_XF1 + 32ull*60*30*8;      // [32][60][30] c64
static constexpr size_t WS_KH1 = WS_XH1 + 32ull*900*8;        // [32][900] c64
static constexpr size_t WS_YH1 = WS_KH1 + 1800ull*8;          // [900][2] c64
static constexpr size_t WS_XT2 = WS_YH1 + 64ull*35990*8;      // [64][Q30] c64
static constexpr size_t WS_XH2 = WS_XT2 + 64ull*60*561*8;     // [64][60][33*17]
static constexpr size_t WS_KH2 = WS_XH2 + 64ull*6545*8;
static constexpr size_t WS_YH2 = WS_KH2 + 6545ull*10*8;
static constexpr size_t WS_XT3 = WS_YH2 + 160ull*6545*8;
static constexpr size_t WS_XH3 = WS_XT3 + 160ull*34*153*8;    // [160][34][17*9]
static constexpr size_t WS_KH3 = WS_XH3 + 160ull*969*8;
static constexpr size_t WS_YH3 = WS_KH3 + 969ull*60*8;
static constexpr size_t WS_XT4 = WS_YH3 + 384ull*969*8;
static constexpr size_t WS_XH4 = WS_XT4 + 384ull*18*45*8;     // [384][18][9*5]
static constexpr size_t WS_KH4 = WS_XH4 + 384ull*165*8;
static constexpr size_t WS_YH4 = WS_KH4 + 165ull*336*8;
static constexpr size_t WS_XT5 = WS_YH4 + 896ull*165*8;
static constexpr size_t WS_XH5 = WS_XT5 + 896ull*10*15*8;     // [896][10][5*3]
static constexpr size_t WS_KH5 = WS_XH5 + 896ull*35*8;
static constexpr size_t WS_YH5 = WS_KH5 + 35ull*1792*8;
static constexpr size_t WS_S5P = WS_YH5 + 2048ull*35*8;
static constexpr size_t WS_TOTAL = WS_S5P + 2048ull*6*4;      // ~67 MB

// ---------------- constant-table offsets (filled at dlopen) ----------------
struct ConstOffs {
  size_t A1, A2, A3, A4, A5;        // float offsets (analysis wigner * quadw)
  size_t S1, S2, S3, S4, S5;        // float offsets (synthesis (2l+1)*wigner)
  size_t WInt;                      // float offset (quadw(3)/36, 6 entries)
  size_t nF;
  size_t Fs2, Fso3;                 // float2 offsets (kernel-FT fourier mats)
  size_t Tw60, Tw34, Tw18, Tw10, Tw6; // float2 offsets (cis(2 pi t / N))
  size_t nC;
};
static ConstOffs CO;
static float*  g_devF = nullptr;
static float2* g_devC = nullptr;

// ============================================================================
// Host: symmetric-tridiagonal eigensolver + Wigner-d builder
// d^l(beta) = exp(beta*G), G real antisym tridiag, G[i][i+1] = +0.5*jp_i.
// Equivalent real symmetric tridiag S (offdiag -0.5*jp) via phase similarity:
// d[a][c] = sum_k V[a,k] V[c,k] * f_{(a-c) mod 4}(beta*lam_k),
//   f = {+cos, +sin, -cos, -sin}.   (verified analytically against exp(bG))
// ============================================================================
static void tqli(double* d, double* e, int n, double* z) {
  // d: diag, e[i]: offdiag(i,i+1) for i<n-1; z: n*n identity -> eigvec columns
  e[n-1] = 0.0;
  for (int l = 0; l < n; l++) {
    int iter = 0;
    int m;
    do {
      for (m = l; m < n-1; m++) {
        double dd = fabs(d[m]) + fabs(d[m+1]);
        if (fabs(e[m]) <= 1e-300 + 1e-14*dd) break;
      }
      if (m != l) {
        if (iter++ == 80) break;
        double g = (d[l+1]-d[l])/(2.0*e[l]);
        double r = hypot(g, 1.0);
        g = d[m]-d[l]+e[l]/(g + (g >= 0.0 ? fabs(r) : -fabs(r)));
        double s = 1.0, c = 1.0, p = 0.0;
        int i;
        r = 1.0;
        for (i = m-1; i >= l; i--) {
          double f = s*e[i], b = c*e[i];
          r = hypot(f, g);
          e[i+1] = r;
          if (r == 0.0) { d[i+1] -= p; e[m] = 0.0; break; }
          s = f/r; c = g/r;
          g = d[i+1]-p;
          r = (d[i]-g)*s + 2.0*c*b;
          p = s*r;
          d[i+1] = g+p;
          g = c*r-b;
          for (int k = 0; k < n; k++) {
            f = z[(size_t)k*n+i+1];
            z[(size_t)k*n+i+1] = s*z[(size_t)k*n+i] + c*f;
            z[(size_t)k*n+i]   = c*z[(size_t)k*n+i] - s*f;
          }
        }
        if (r == 0.0 && i >= l) continue;
        d[l] -= p; e[l] = g; e[m] = 0.0;
      }
    } while (m != l);
  }
}

struct Builder {
  std::vector<std::vector<double>> V, Lam;
  bool useExpm[30];

  Builder() {
    V.resize(30); Lam.resize(30);
    for (int l = 0; l < 30; l++) {
      int n = 2*l+1;
      std::vector<double> d(n, 0.0), e(n, 0.0), z((size_t)n*n, 0.0);
      for (int i = 0; i < n; i++) z[(size_t)i*n+i] = 1.0;
      for (int i = 0; i+1 < n; i++) {
        double m = (double)i - l;
        e[i] = -0.5*sqrt((double)l*(l+1) - m*(m+1.0));
      }
      if (n > 1) tqli(d.data(), e.data(), n, z.data());
      V[l] = std::move(z); Lam[l] = std::move(d);
    }
    // validate eigen path per l against closed-form corner + orthonormality
    std::vector<double> t((size_t)59*59);
    for (int l = 0; l < 30; l++) {
      useExpm[l] = false;
      if (l == 0) continue;
      int n = 2*l+1;
      eigD(l, 0.77, t.data());
      double corner = pow(cos(0.385), 2.0*l);   // d_{l,l} = cos(b/2)^(2l)
      double err = fabs(t[0] - corner) + fabs(t[(size_t)(n-1)*n + (n-1)] - corner);
      double s = 0.0;
      for (int c = 0; c < n; c++) s += t[c]*t[c];
      err += fabs(s - 1.0);
      if (!(err < 1e-8)) useExpm[l] = true;
    }
  }

  void eigD(int l, double beta, double* out) {
    int n = 2*l+1;
    const double* Vp = V[l].data();
    const double* lam = Lam[l].data();
    double ck[64], sk[64];
    for (int k = 0; k < n; k++) { ck[k] = cos(beta*lam[k]); sk[k] = sin(beta*lam[k]); }
    for (int a = 0; a < n; a++) {
      const double* va = Vp + (size_t)a*n;
      for (int c = 0; c < n; c++) {
        const double* vc = Vp + (size_t)c*n;
        int r = ((a - c) % 4 + 4) % 4;
        const double* f = (r & 1) ? sk : ck;
        double s = 0.0;
        for (int k = 0; k < n; k++) s += va[k]*vc[k]*f[k];
        out[(size_t)a*n + c] = (r >= 2) ? -s : s;
      }
    }
  }

  // scaling-and-squaring exp(beta*G) fallback (unambiguous, slower)
  void expmD(int l, double beta, double* out) {
    int n = 2*l+1;
    int s = 0; double bl = fabs(beta)*(double)l + 1e-12;
    while (bl > 0.25) { bl *= 0.5; s++; }
    double sc = ldexp(beta, -s);
    std::vector<double> sup(n > 1 ? n-1 : 0);
    for (int i = 0; i+1 < n; i++) {
      double m = (double)i - l;
      sup[i] = 0.5*sqrt((double)l*(l+1) - m*(m+1.0))*sc;
    }
    std::vector<double> term((size_t)n*n, 0.0), acc((size_t)n*n, 0.0), t2((size_t)n*n);
    for (int i = 0; i < n; i++) { term[(size_t)i*n+i] = 1.0; acc[(size_t)i*n+i] = 1.0; }
    for (int k = 1; k <= 16; k++) {
      for (int r = 0; r < n; r++)
        for (int c = 0; c < n; c++) {
          double v = 0.0;
          if (c > 0)   v += term[(size_t)r*n + c-1]*sup[c-1];
          if (c+1 < n) v -= term[(size_t)r*n + c+1]*sup[c];
          t2[(size_t)r*n+c] = v/(double)k;
        }
      term.swap(t2);
      for (size_t i2 = 0; i2 < (size_t)n*n; i2++) acc[i2] += term[i2];
    }
    for (int t = 0; t < s; t++) {
      for (int r = 0; r < n; r++)
        for (int c = 0; c < n; c++) {
          double v = 0.0;
          for (int k = 0; k < n; k++) v += acc[(size_t)r*n+k]*acc[(size_t)k*n+c];
          t2[(size_t)r*n+c] = v;
        }
      acc.swap(t2);
    }
    std::memcpy(out, acc.data(), sizeof(double)*(size_t)n*n);
  }

  void buildD(int l, double beta, double* out) {
    if (useExpm[l]) expmD(l, beta, out); else eigD(l, beta, out);
  }
};

static std::vector<double> quadw_h(int b) {
  std::vector<double> w(2*b);
  for (int j = 0; j < 2*b; j++) {
    double s = 0;
    for (int k = 0; k < b; k++)
      s += sin(DPI*(2*j+1)*(2*k+1)/(4.0*b))/(double)(2*k+1);
    w[j] = (2.0/b)*sin(DPI*(2*j+1)/(4.0*b))*s;
  }
  return w;
}

static void build_all() {
  // ---- offsets ----
  size_t o = 0;
  CO.A1 = o; o += 60ull*900;
  CO.A2 = o; o += 60ull*OQh(17);
  CO.A3 = o; o += 34ull*OQh(9);
  CO.A4 = o; o += 18ull*OQh(5);
  CO.A5 = o; o += 10ull*OQh(3);
  CO.S1 = o; o += 60ull*OQh(30);
  CO.S2 = o; o += 34ull*OQh(17);
  CO.S3 = o; o += 18ull*OQh(9);
  CO.S4 = o; o += 10ull*OQh(5);
  CO.S5 = o; o +=  6ull*OQh(3);
  CO.WInt = o; o += 8;
  CO.nF = o;
  size_t c = 0;
  CO.Fs2  = c; c += 6ull*900;
  CO.Fso3 = c; c += 36ull*OQh(17);
  CO.Tw60 = c; c += 60; CO.Tw34 = c; c += 34; CO.Tw18 = c; c += 18;
  CO.Tw10 = c; c += 10; CO.Tw6  = c; c += 6;
  CO.nC = c;

  std::vector<float> HF(CO.nF, 0.f);
  std::vector<float> HC(2*CO.nC, 0.f);   // interleaved float2

  Builder B;
  auto betas = [](int b){ std::vector<double> v(2*b);
    for (int j = 0; j < 2*b; j++) v[j] = DPI*(2*j+1)/(4.0*b); return v; };
  auto w30 = quadw_h(30), w17 = quadw_h(17), w9 = quadw_h(9), w5 = quadw_h(5), w3 = quadw_h(3);
  std::vector<double> tmp((size_t)59*59);

  // grid betas_of(30): dS1 (l<30), dA2 (l<17), dA1 (l<30, column c=l)
  { auto bs = betas(30);
    for (int l = 0; l < 30; l++) { int n = 2*l+1;
      for (int j = 0; j < 60; j++) {
        B.buildD(l, bs[j], tmp.data());
        float* dst = HF.data() + CO.S1 + 60ull*OQh(l) + (size_t)j*n*n;
        for (int i2 = 0; i2 < n*n; i2++) dst[i2] = (float)((2*l+1)*tmp[i2]);
        if (l < 17) {
          float* dA = HF.data() + CO.A2 + 60ull*OQh(l) + (size_t)j*n*n;
          for (int i2 = 0; i2 < n*n; i2++) dA[i2] = (float)(tmp[i2]*w30[j]);
        }
        float* dA1 = HF.data() + CO.A1 + 60ull*l*l + (size_t)j*n;
        for (int mi = 0; mi < n; mi++) dA1[mi] = (float)(tmp[(size_t)mi*n + l]*w30[j]);
      } } }
  // grid betas_of(17): dS2 (l<17), dA3 (l<9)
  { auto bs = betas(17);
    for (int l = 0; l < 17; l++) { int n = 2*l+1;
      for (int j = 0; j < 34; j++) {
        B.buildD(l, bs[j], tmp.data());
        float* dst = HF.data() + CO.S2 + 34ull*OQh(l) + (size_t)j*n*n;
        for (int i2 = 0; i2 < n*n; i2++) dst[i2] = (float)((2*l+1)*tmp[i2]);
        if (l < 9) {
          float* dA = HF.data() + CO.A3 + 34ull*OQh(l) + (size_t)j*n*n;
          for (int i2 = 0; i2 < n*n; i2++) dA[i2] = (float)(tmp[i2]*w17[j]);
        } } } }
  // grid betas_of(9): dS3 (l<9), dA4 (l<5)
  { auto bs = betas(9);
    for (int l = 0; l < 9; l++) { int n = 2*l+1;
      for (int j = 0; j < 18; j++) {
        B.buildD(l, bs[j], tmp.data());
        float* dst = HF.data() + CO.S3 + 18ull*OQh(l) + (size_t)j*n*n;
        for (int i2 = 0; i2 < n*n; i2++) dst[i2] = (float)((2*l+1)*tmp[i2]);
        if (l < 5) {
          float* dA = HF.data() + CO.A4 + 18ull*OQh(l) + (size_t)j*n*n;
          for (int i2 = 0; i2 < n*n; i2++) dA[i2] = (float)(tmp[i2]*w9[j]);
        } } } }
  // grid betas_of(5): dS4 (l<5), dA5 (l<3)
  { auto bs = betas(5);
    for (int l = 0; l < 5; l++) { int n = 2*l+1;
      for (int j = 0; j < 10; j++) {
        B.buildD(l, bs[j], tmp.data());
        float* dst = HF.data() + CO.S4 + 10ull*OQh(l) + (size_t)j*n*n;
        for (int i2 = 0; i2 < n*n; i2++) dst[i2] = (float)((2*l+1)*tmp[i2]);
        if (l < 3) {
          float* dA = HF.data() + CO.A5 + 10ull*OQh(l) + (size_t)j*n*n;
          for (int i2 = 0; i2 < n*n; i2++) dA[i2] = (float)(tmp[i2]*w5[j]);
        } } } }
  // grid betas_of(3): dS5 (l<3)
  { auto bs = betas(3);
    for (int l = 0; l < 3; l++) { int n = 2*l+1;
      for (int j = 0; j < 6; j++) {
        B.buildD(l, bs[j], tmp.data());
        float* dst = HF.data() + CO.S5 + 6ull*OQh(l) + (size_t)j*n*n;
        for (int i2 = 0; i2 < n*n; i2++) dst[i2] = (float)((2*l+1)*tmp[i2]);
      } } }
  // beta = pi/16: Fs2 (l<30, column c=l), Fso3 (l<17 full)
  { double beta = DPI/16.0;
    for (int l = 0; l < 30; l++) { int n = 2*l+1;
      B.buildD(l, beta, tmp.data());
      for (int p = 0; p < 6; p++) {
        double al = 2.0*DPI*p/6.0;
        for (int mi = 0; mi < n; mi++) {
          double ph = al*(double)(mi - l);
          double dr = tmp[(size_t)mi*n + l];
          size_t off = CO.Fs2 + 6ull*l*l + (size_t)p*n + mi;
          HC[2*off]   = (float)(dr*cos(ph));
          HC[2*off+1] = (float)(dr*sin(ph));
        } }
      if (l < 17) {
        for (int p = 0; p < 36; p++) {
          double al = 2.0*DPI*(p/6)/6.0, ga = 2.0*DPI*(p%6)/6.0;
          for (int mi = 0; mi < n; mi++)
            for (int ni = 0; ni < n; ni++) {
              double ph = al*(double)(mi - l) + ga*(double)(ni - l);
              double dr = tmp[(size_t)mi*n + ni];
              size_t off = CO.Fso3 + 36ull*OQh(l) + (size_t)p*n*n + (size_t)mi*n + ni;
              HC[2*off]   = (float)(dr*cos(ph));
              HC[2*off+1] = (float)(dr*sin(ph));
            } } } } }
  // twiddles cis(2 pi t / N)
  auto fillTw = [&](size_t ofs, int N){
    for (int t = 0; t < N; t++) {
      HC[2*(ofs+t)]   = (float)cos(2.0*DPI*t/N);
      HC[2*(ofs+t)+1] = (float)sin(2.0*DPI*t/N);
    } };
  fillTw(CO.Tw60, 60); fillTw(CO.Tw34, 34); fillTw(CO.Tw18, 18);
  fillTw(CO.Tw10, 10); fillTw(CO.Tw6, 6);
  for (int j = 0; j < 6; j++) HF[CO.WInt + j] = (float)(w3[j]/36.0);

  // ---- upload ----
  size_t fb = CO.nF * sizeof(float);
  size_t fbA = (fb + 255) & ~(size_t)255;
  size_t cb = CO.nC * sizeof(float2);
  void* base = nullptr;
  if (hipMalloc(&base, fbA + cb) != hipSuccess || !base) return;
  if (hipMemcpy(base, HF.data(), fb, hipMemcpyHostToDevice) != hipSuccess) return;
  if (hipMemcpy((char*)base + fbA, HC.data(), cb, hipMemcpyHostToDevice) != hipSuccess) return;
  (void)hipDeviceSynchronize();
  g_devF = (float*)base;
  g_devC = (float2*)((char*)base + fbA);
}
namespace { struct InitOnce { InitOnce(){ build_all(); } } g_once; }

// ============================================================================
// Device helpers
// ============================================================================
__device__ __forceinline__ int OQ(int l) { return l*(4*l*l - 1)/3; }
__device__ __forceinline__ int lFromQ(int q, int L) {
  int l = 0;
  while (l+1 < L && OQ(l+1) <= q) l++;
  return l;
}
__device__ __forceinline__ int lsq(int q) {
  int l = (int)sqrtf((float)q);
  while ((l+1)*(l+1) <= q) l++;
  while (l*l > q) l--;
  return l;
}

// ---------------- kernel FT: s2 ----------------
__global__ __launch_bounds__(256) void k_kh_s2(
    const float* __restrict__ ks2, const float2* __restrict__ F, float2* __restrict__ kh)
{
  int id = blockIdx.x*blockDim.x + threadIdx.x;
  if (id >= 1800) return;
  int q = id >> 1, o = id & 1;
  int l = lsq(q); int W = 2*l+1; int mi = q - l*l;
  const float2* Fb = F + 6ull*l*l;
  float ax = 0.f, ay = 0.f;
  for (int p = 0; p < 6; p++) {
    float kv = ks2[o*6 + p];             // i = 0 (single input channel)
    float2 f = Fb[p*W + mi];
    ax += kv*f.x; ay += kv*f.y;
  }
  kh[(size_t)q*2 + o] = make_float2(ax, ay);
}

// ---------------- kernel FT: so3 ----------------
__global__ __launch_bounds__(256) void k_kh_so3(
    const float* __restrict__ kk, const float2* __restrict__ F,
    float2* __restrict__ kh, int L, int fi, int fo)
{
  int id = blockIdx.x*blockDim.x + threadIdx.x;
  int ff = fi*fo;
  if (id >= OQ(L)*ff) return;
  int q = id / ff, r = id - q*ff;
  int i = r / fo, o = r - i*fo;
  int l = lFromQ(q, L); int W = 2*l+1; int W21 = W*W;
  int rem = q - OQ(l);
  const float2* Fb = F + 36ull*OQ(l) + rem;
  const float* kb = kk + (size_t)(i*fo + o)*36;
  float ax = 0.f, ay = 0.f;
  for (int p = 0; p < 36; p++) {
    float kv = kb[p];
    float2 f = Fb[(size_t)p*W21];
    ax += kv*f.x; ay += kv*f.y;
  }
  kh[(size_t)q*ff + r] = make_float2(ax, ay);
}

// ---------------- stage-1 analysis: alpha FFT (real input, m=0..29) --------
__global__ __launch_bounds__(64) void k_s1_fftA(
    const float* __restrict__ x, const float2* __restrict__ tw, float2* __restrict__ XF1)
{
  __shared__ float row[60];
  int b = blockIdx.x / 60, j = blockIdx.x - b*60;
  int t = threadIdx.x;
  if (t < 60) row[t] = x[((size_t)b*60 + j)*60 + t];
  __syncthreads();
  if (t < 30) {
    float ax = 0.f, ay = 0.f;
    int ti = 0;                       // (a*m) mod 60, incremental
    for (int a = 0; a < 60; a++) {
      float2 w = tw[ti];
      ax += row[a]*w.x; ay -= row[a]*w.y;   // e^{-2 pi i a m / 60}
      ti += t; if (ti >= 60) ti -= 60;
    }
    XF1[((size_t)b*60 + j)*30 + t] = make_float2(ax, ay);
  }
}

// ---------------- stage-1 beta contraction (wigner * quadw) ----------------
__global__ __launch_bounds__(256) void k_s1_coef(
    const float2* __restrict__ XF1, const float* __restrict__ dA1, float2* __restrict__ xh1)
{
  int id = blockIdx.x*blockDim.x + threadIdx.x;
  if (id >= 32*900) return;
  int b = id / 900, q = id - b*900;
  int l = lsq(q); int W = 2*l+1; int mi = q - l*l; int m = mi - l;
  const float* dp = dA1 + 60ull*l*l + mi;
  const float2* xb = XF1 + (size_t)b*60*30;
  int ma = m >= 0 ? m : -m;
  float sg = m >= 0 ? 1.f : -1.f;     // negative m via conj (real input)
  float ax = 0.f, ay = 0.f;
  for (int j = 0; j < 60; j++) {
    float2 xf = xb[j*30 + ma];
    float d = dp[(size_t)j*W];
    ax += d*xf.x; ay += sg*d*xf.y;
  }
  xh1[id] = make_float2(ax, ay);
}

// ---------------- stage-1 spectral product (outer product, conj kernel) ----
__global__ __launch_bounds__(256) void k_s1_yh(
    const float2* __restrict__ xh1, const float2* __restrict__ kh1, float2* __restrict__ yh1)
{
  int id = blockIdx.x*blockDim.x + threadIdx.x;
  if (id >= 64*35990) return;
  int bo = id / 35990, q = id - bo*35990;
  int b = bo >> 1, o = bo & 1;
  int l = lFromQ(q, 30); int W = 2*l+1;
  int rem = q - OQ(l); int mi = rem / W, ni = rem - mi*W;
  float2 xv = xh1[(size_t)b*900 + l*l + mi];
  float2 kv = kh1[(size_t)(l*l + ni)*2 + o];
  yh1[id] = make_float2(xv.x*kv.x + xv.y*kv.y, xv.y*kv.x - xv.x*kv.y); // x*conj(k)
}

// ---------------- generic spectral product for so3 stages ------------------
__global__ __launch_bounds__(256) void k_yh(
    const float2* __restrict__ xh, const float2* __restrict__ kh,
    float2* __restrict__ yh, int L, int fi, int fo, int Qtot)
{
  int id = blockIdx.x*blockDim.x + threadIdx.x;
  if (id >= 32*fo*Qtot) return;
  int bo = id / Qtot, q = id - bo*Qtot;
  int b = bo / fo, o = bo - b*fo;
  int l = lFromQ(q, L); int W = 2*l+1;
  int rem = q - OQ(l); int mi = rem / W, ni = rem - mi*W;
  int ff = fi*fo;
  const float2* xb = xh + ((size_t)b*fi)*Qtot + OQ(l) + mi*W;
  const float2* kb = kh + ((size_t)(OQ(l) + ni*W))*ff + o;
  float ax = 0.f, ay = 0.f;
  for (int i = 0; i < fi; i++) {
    const float2* xrow = xb + (size_t)i*Qtot;
    const float2* krow = kb + (size_t)i*fo;
    for (int k = 0; k < W; k++) {
      float2 xv = xrow[k];
      float2 kv = krow[(size_t)k*ff];
      ax += xv.x*kv.x + xv.y*kv.y;          // x * conj(k)
      ay += xv.y*kv.x - xv.x*kv.y;
    }
  }
  yh[id] = make_float2(ax, ay);
}

// ---------------- generic beta contraction for so3 stages ------------------
__global__ __launch_bounds__(256) void k_coef(
    const float2* __restrict__ xt, const float* __restrict__ dA,
    float2* __restrict__ xh, int L, int nj, int KT, int MT, int Qtot, int nbi)
{
  int id = blockIdx.x*blockDim.x + threadIdx.x;
  if (id >= nbi*Qtot) return;
  int bi = id / Qtot, q = id - bi*Qtot;
  int l = lFromQ(q, L); int W = 2*l+1; int W21 = W*W;
  int rem = q - OQ(l); int mi = rem / W, ki = rem - mi*W;
  int m = mi - l, ks = ki - l;
  const float* dAp = dA + (size_t)nj*OQ(l) + rem;
  int MTKT = MT*KT;
  int pidx; float sgn;
  if (ks >= 0) { pidx = (m + (KT-1))*KT + ks;  sgn =  1.f; }
  else         { pidx = (-m + (KT-1))*KT - ks; sgn = -1.f; } // joint-Hermitian conj
  const float2* xb = xt + (size_t)bi*nj*MTKT + pidx;
  float ax = 0.f, ay = 0.f;
  for (int j = 0; j < nj; j++) {
    float2 xv = xb[(size_t)j*MTKT];
    float d = dAp[(size_t)j*W21];
    ax += d*xv.x; ay += sgn*d*xv.y;
  }
  xh[id] = make_float2(ax, ay);
}

// ---------------- fused synthesis: scatter -> iDFT2 -> ReLU -> fwd DFT2 ----
// one block per (batch*channel, beta_j) slab; LDS-resident throughout.
__global__ __launch_bounds__(256) void k_synth(
    const float2* __restrict__ yh, const float* __restrict__ dS,
    const float2* __restrict__ twN, float2* __restrict__ xt,
    float* __restrict__ s5p, const float* __restrict__ wInt,
    int Bq, int N, int KT, int MT, int Qtot, int integrate)
{
  extern __shared__ char smem[];
  const int W2 = 2*Bq - 1;
  size_t r0 = (size_t)W2*W2*8;
  { size_t alt = (size_t)4*N*N + (size_t)8*N*KT; if (alt > r0) r0 = alt; }
  size_t treg = (size_t)8*N*W2;
  { size_t t2 = (size_t)4*blockDim.x; if (t2 > treg) treg = t2; }
  float2* P   = (float2*)smem;
  float2* Tm  = (float2*)(smem + r0);
  float2* twl = (float2*)(smem + r0 + treg);
  const int tpb = blockDim.x, tid = threadIdx.x;

  // bijective XCD swizzle (gridDim.x % 8 == 0 for all stages)
  int nwg = gridDim.x, bidx = blockIdx.x;
  int per = nwg >> 3;
  int swz = (bidx & 7)*per + (bidx >> 3);
  int bo = swz / N, j = swz - bo*N;

  for (int t = tid; t < N; t += tpb) twl[t] = twN[t];

  // --- Wigner scatter: P[m][n] = sum_l yh[l,m,n] * (2l+1) d^l_{m,n}(beta_j)
  const float2* yhb = yh + (size_t)bo*Qtot;
  for (int idx = tid; idx < W2*W2; idx += tpb) {
    int pm = idx / W2, pn = idx - pm*W2;
    int m = pm - (Bq-1), n = pn - (Bq-1);
    int am = m < 0 ? -m : m, an = n < 0 ? -n : n;
    int lmin = am > an ? am : an;
    float ax = 0.f, ay = 0.f;
    int base = OQ(lmin);
    for (int l = lmin; l < Bq; l++) {
      int Wl = 2*l+1;
      int e = base + (m+l)*Wl + (n+l);
      float2 y = yhb[e];
      float d = dS[(size_t)N*base + (size_t)j*Wl*Wl + (size_t)(m+l)*Wl + (n+l)];
      ax += d*y.x; ay += d*y.y;
      base += Wl*Wl;
    }
    P[idx] = make_float2(ax, ay);
  }
  __syncthreads();

  // --- iDFT along m (alpha), 2 output rows per thread-iteration
  int nag = N >> 1;
  for (int idx = tid; idx < nag*W2; idx += tpb) {
    int ag = idx / W2, pn = idx - ag*W2;
    int a0 = ag*2, a1 = a0 + 1;
    int m0 = -(Bq-1);
    int t0 = (int)(((long long)a0*m0) % N); if (t0 < 0) t0 += N;
    int t1 = (int)(((long long)a1*m0) % N); if (t1 < 0) t1 += N;
    float r0x=0.f, r0y=0.f, r1x=0.f, r1y=0.f;
    const float2* pp = P + pn;
    for (int pm = 0; pm < W2; pm++) {
      float2 p = pp[(size_t)pm*W2];
      float2 w0 = twl[t0], w1 = twl[t1];
      r0x += p.x*w0.x - p.y*w0.y; r0y += p.x*w0.y + p.y*w0.x;
      r1x += p.x*w1.x - p.y*w1.y; r1y += p.x*w1.y + p.y*w1.x;
      t0 += a0; if (t0 >= N) t0 -= N;
      t1 += a1; if (t1 >= N) t1 -= N;
    }
    Tm[(size_t)a0*W2 + pn] = make_float2(r0x, r0y);
    Tm[(size_t)a1*W2 + pn] = make_float2(r1x, r1y);
  }
  __syncthreads();

  // --- iDFT along n (gamma), real part + ReLU  (overwrites P region)
  float* S = (float*)smem;
  for (int idx = tid; idx < N*N; idx += tpb) {
    int a = idx / N, cc = idx - a*N;
    const float2* Trow = Tm + (size_t)a*W2;
    int t = (int)(((long long)cc*(-(Bq-1))) % N); if (t < 0) t += N;
    float acc = 0.f;
    for (int pn = 0; pn < W2; pn++) {
      float2 Tv = Trow[pn]; float2 w = twl[t];
      acc += Tv.x*w.x - Tv.y*w.y;
      t += cc; if (t >= N) t -= N;
    }
    S[idx] = acc > 0.f ? acc : 0.f;
  }
  __syncthreads();

  if (integrate) {
    float part = 0.f;
    for (int idx = tid; idx < N*N; idx += tpb) part += S[idx];
    float* red = (float*)Tm;
    red[tid] = part;
    __syncthreads();
    for (int off2 = tpb >> 1; off2 > 0; off2 >>= 1) {
      if (tid < off2) red[tid] += red[tid + off2];
      __syncthreads();
    }
    if (tid == 0) s5p[bo*N + j] = red[0]*wInt[j];
  } else {
    // --- forward DFT along gamma, truncated to k=0..KT-1
    float2* U = (float2*)(smem + (size_t)4*N*N);
    for (int idx = tid; idx < N*KT; idx += tpb) {
      int a = idx / KT, k = idx - a*KT;
      const float* Srow = S + (size_t)a*N;
      float ux = 0.f, uy = 0.f;
      int t = 0;
      for (int cc = 0; cc < N; cc++) {
        float sv = Srow[cc]; float2 w = twl[t];
        ux += sv*w.x; uy -= sv*w.y;           // conj
        t += k; if (t >= N) t -= N;
      }
      U[idx] = make_float2(ux, uy);
    }
    __syncthreads();
    // --- forward DFT along alpha, m = -(KT-1)..(KT-1)
    float2* xtb = xt + ((size_t)bo*N + j)*((size_t)MT*KT);
    for (int idx = tid; idx < MT*KT; idx += tpb) {
      int pm2 = idx / KT, k = idx - pm2*KT;
      int m = pm2 - (KT-1);
      float ax = 0.f, ay = 0.f;
      int t = 0;
      for (int a = 0; a < N; a++) {
        float2 u = U[(size_t)a*KT + k]; float2 w = twl[t];
        ax += u.x*w.x + u.y*w.y;              // u * conj(w)
        ay += u.y*w.x - u.x*w.y;
        t += m; if (t < 0) t += N; else if (t >= N) t -= N;
      }
      xtb[idx] = make_float2(ax, ay);
    }
  }
}

// ---------------- head: integrate-reduce + 3x (batchnorm, linear) ----------
__global__ __launch_bounds__(256) void k_mlp(
    const float* __restrict__ s5p,
    const float* __restrict__ g1, const float* __restrict__ be1,
    const float* __restrict__ w1, const float* __restrict__ b1,
    const float* __restrict__ g2, const float* __restrict__ be2,
    const float* __restrict__ w2, const float* __restrict__ b2,
    const float* __restrict__ g3, const float* __restrict__ be3,
    const float* __restrict__ w3, const float* __restrict__ b3,
    float* __restrict__ out)
{
  __shared__ float A[2048], Bs[2048], C[1024], mu[64], iv[64];
  int tid = threadIdx.x;
  for (int idx = tid; idx < 2048; idx += 256) {
    float s = 0.f;
    #pragma unroll
    for (int j = 0; j < 6; j++) s += s5p[idx*6 + j];
    A[idx] = s;
  }
  __syncthreads();
  if (tid < 64) {                                 // bn1
    float m = 0.f; for (int b = 0; b < 32; b++) m += A[b*64 + tid]; m *= (1.f/32);
    float v = 0.f; for (int b = 0; b < 32; b++) { float d = A[b*64+tid]-m; v += d*d; } v *= (1.f/32);
    mu[tid] = m; iv[tid] = rsqrtf(v + 1e-5f)*g1[tid];
  }
  __syncthreads();
  for (int idx = tid; idx < 2048; idx += 256) {
    int f = idx & 63;
    A[idx] = (A[idx]-mu[f])*iv[f] + be1[f];
  }
  __syncthreads();
  for (int idx = tid; idx < 2048; idx += 256) {   // linear1 + relu
    int b = idx >> 6, fo = idx & 63;
    float s = b1[fo];
    for (int f = 0; f < 64; f++) s += A[b*64+f]*w1[f*64+fo];
    Bs[idx] = fmaxf(s, 0.f);
  }
  __syncthreads();
  if (tid < 64) {                                 // bn2
    float m = 0.f; for (int b = 0; b < 32; b++) m += Bs[b*64+tid]; m *= (1.f/32);
    float v = 0.f; for (int b = 0; b < 32; b++) { float d = Bs[b*64+tid]-m; v += d*d; } v *= (1.f/32);
    mu[tid] = m; iv[tid] = rsqrtf(v + 1e-5f)*g2[tid];
  }
  __syncthreads();
  for (int idx = tid; idx < 2048; idx += 256) {
    int f = idx & 63;
    Bs[idx] = (Bs[idx]-mu[f])*iv[f] + be2[f];
  }
  __syncthreads();
  for (int idx = tid; idx < 1024; idx += 256) {   // linear2 + relu
    int b = idx >> 5, fo = idx & 31;
    float s = b2[fo];
    for (int f = 0; f < 64; f++) s += Bs[b*64+f]*w2[f*32+fo];
    C[idx] = fmaxf(s, 0.f);
  }
  __syncthreads();
  if (tid < 32) {                                 // bn3
    float m = 0.f; for (int b = 0; b < 32; b++) m += C[b*32+tid]; m *= (1.f/32);
    float v = 0.f; for (int b = 0; b < 32; b++) { float d = C[b*32+tid]-m; v += d*d; } v *= (1.f/32);
    mu[tid] = m; iv[tid] = rsqrtf(v + 1e-5f)*g3[tid];
  }
  __syncthreads();
  for (int idx = tid; idx < 1024; idx += 256) {
    int f = idx & 31;
    C[idx] = (C[idx]-mu[f])*iv[f] + be3[f];
  }
  __syncthreads();
  for (int idx = tid; idx < 320; idx += 256) {    // linear3 (no relu)
    int b = idx/10, cc = idx - b*10;
    float s = b3[cc];
    for (int f = 0; f < 32; f++) s += C[b*32+f]*w3[f*10+cc];
    out[idx] = s;
  }
}

// ============================================================================
// launch
// ============================================================================
static size_t synth_smem(int Bq, int N, int KT, int tpb) {
  int W2 = 2*Bq - 1;
  size_t r0 = (size_t)W2*W2*8;
  size_t alt = (size_t)4*N*N + (size_t)8*N*KT; if (alt > r0) r0 = alt;
  size_t tr = (size_t)8*N*W2; size_t t2 = (size_t)4*tpb; if (t2 > tr) tr = t2;
  return r0 + tr + (size_t)8*N;
}
static inline int cdiv_h(int a, int b) { return (a + b - 1)/b; }

extern "C" void kernel_launch(void* const* d_in, const int* in_sizes, int n_in,
                              void* d_out, int out_size, void* d_ws, size_t ws_size,
                              hipStream_t stream) {
  (void)in_sizes; (void)n_in; (void)out_size;
  if (!g_devF || !g_devC || ws_size < WS_TOTAL) return;

  const float* x    = (const float*)d_in[0];
  const float* ks2  = (const float*)d_in[1];
  const float* k1   = (const float*)d_in[2];
  const float* k2   = (const float*)d_in[3];
  const float* k3   = (const float*)d_in[4];
  const float* k4   = (const float*)d_in[5];
  const float* g1   = (const float*)d_in[6],  *be1 = (const float*)d_in[7];
  const float* w1   = (const float*)d_in[8],  *b1  = (const float*)d_in[9];
  const float* g2   = (const float*)d_in[10], *be2 = (const float*)d_in[11];
  const float* w2   = (const float*)d_in[12], *b2  = (const float*)d_in[13];
  const float* g3   = (const float*)d_in[14], *be3 = (const float*)d_in[15];
  const float* w3   = (const float*)d_in[16], *b3  = (const float*)d_in[17];
  float* out = (float*)d_out;
  char* ws = (char*)d_ws;

  float2* XF1 = (float2*)(ws + WS_XF1);
  float2* xh1 = (float2*)(ws + WS_XH1);
  float2* kh1 = (float2*)(ws + WS_KH1);
  float2* yh1 = (float2*)(ws + WS_YH1);
  float2* xt2 = (float2*)(ws + WS_XT2);
  float2* xh2 = (float2*)(ws + WS_XH2);
  float2* kh2 = (float2*)(ws + WS_KH2);
  float2* yh2 = (float2*)(ws + WS_YH2);
  float2* xt3 = (float2*)(ws + WS_XT3);
  float2* xh3 = (float2*)(ws + WS_XH3);
  float2* kh3 = (float2*)(ws + WS_KH3);
  float2* yh3 = (float2*)(ws + WS_YH3);
  float2* xt4 = (float2*)(ws + WS_XT4);
  float2* xh4 = (float2*)(ws + WS_XH4);
  float2* kh4 = (float2*)(ws + WS_KH4);
  float2* yh4 = (float2*)(ws + WS_YH4);
  float2* xt5 = (float2*)(ws + WS_XT5);
  float2* xh5 = (float2*)(ws + WS_XH5);
  float2* kh5 = (float2*)(ws + WS_KH5);
  float2* yh5 = (float2*)(ws + WS_YH5);
  float*  s5p = (float*) (ws + WS_S5P);

  const float* dA1p = g_devF + CO.A1; const float* dA2p = g_devF + CO.A2;
  const float* dA3p = g_devF + CO.A3; const float* dA4p = g_devF + CO.A4;
  const float* dA5p = g_devF + CO.A5;
  const float* dS1p = g_devF + CO.S1; const float* dS2p = g_devF + CO.S2;
  const float* dS3p = g_devF + CO.S3; const float* dS4p = g_devF + CO.S4;
  const float* dS5p = g_devF + CO.S5;
  const float* wIntp = g_devF + CO.WInt;
  const float2* Fs2p  = g_devC + CO.Fs2;
  const float2* Fso3p = g_devC + CO.Fso3;
  const float2* tw60p = g_devC + CO.Tw60; const float2* tw34p = g_devC + CO.Tw34;
  const float2* tw18p = g_devC + CO.Tw18; const float2* tw10p = g_devC + CO.Tw10;
  const float2* tw6p  = g_devC + CO.Tw6;

  constexpr int Q30 = OQh(30), Q17 = OQh(17), Q9 = OQh(9), Q5 = OQh(5), Q3 = OQh(3);

  // kernel FTs (runtime weights x constant Fourier matrices)
  k_kh_s2 <<<cdiv_h(1800,256),      256, 0, stream>>>(ks2, Fs2p,  kh1);
  k_kh_so3<<<cdiv_h(Q17*10,256),    256, 0, stream>>>(k1, Fso3p, kh2, 17, 2, 5);
  k_kh_so3<<<cdiv_h(Q9*60,256),     256, 0, stream>>>(k2, Fso3p, kh3, 9, 5, 12);
  k_kh_so3<<<cdiv_h(Q5*336,256),    256, 0, stream>>>(k3, Fso3p, kh4, 5, 12, 28);
  k_kh_so3<<<cdiv_h(Q3*1792,256),   256, 0, stream>>>(k4, Fso3p, kh5, 3, 28, 64);

  // stage 1: s2 analysis + spectral product
  k_s1_fftA<<<32*60, 64, 0, stream>>>(x, tw60p, XF1);
  k_s1_coef<<<cdiv_h(32*900,256), 256, 0, stream>>>(XF1, dA1p, xh1);
  k_s1_yh  <<<cdiv_h(64*Q30,256), 256, 0, stream>>>(xh1, kh1, yh1);

  // stage boundaries: fused synth (scatter->ifft2->relu->fft2) + coef + yh
  k_synth<<<64*60,  256, synth_smem(30,60,17,256), stream>>>(yh1, dS1p, tw60p, xt2, nullptr, nullptr, 30, 60, 17, 33, Q30, 0);
  k_coef <<<cdiv_h(64*Q17,256),  256, 0, stream>>>(xt2, dA2p, xh2, 17, 60, 17, 33, Q17, 64);
  k_yh   <<<cdiv_h(160*Q17,256), 256, 0, stream>>>(xh2, kh2, yh2, 17, 2, 5, Q17);

  k_synth<<<160*34, 256, synth_smem(17,34,9,256), stream>>>(yh2, dS2p, tw34p, xt3, nullptr, nullptr, 17, 34, 9, 17, Q17, 0);
  k_coef <<<cdiv_h(160*Q9,256),  256, 0, stream>>>(xt3, dA3p, xh3, 9, 34, 9, 17, Q9, 160);
  k_yh   <<<cdiv_h(384*Q9,256),  256, 0, stream>>>(xh3, kh3, yh3, 9, 5, 12, Q9);

  k_synth<<<384*18, 128, synth_smem(9,18,5,128), stream>>>(yh3, dS3p, tw18p, xt4, nullptr, nullptr, 9, 18, 5, 9, Q9, 0);
  k_coef <<<cdiv_h(384*Q5,256),  256, 0, stream>>>(xt4, dA4p, xh4, 5, 18, 5, 9, Q5, 384);
  k_yh   <<<cdiv_h(896*Q5,256),  256, 0, stream>>>(xh4, kh4, yh4, 5, 12, 28, Q5);

  k_synth<<<896*10, 64, synth_smem(5,10,3,64), stream>>>(yh4, dS4p, tw10p, xt5, nullptr, nullptr, 5, 10, 3, 5, Q5, 0);
  k_coef <<<cdiv_h(896*Q3,256),  256, 0, stream>>>(xt5, dA5p, xh5, 3, 10, 3, 5, Q3, 896);
  k_yh   <<<cdiv_h(2048*Q3,256), 256, 0, stream>>>(xh5, kh5, yh5, 3, 28, 64, Q3);

  // final synthesis fused with so3_integrate
  k_synth<<<2048*6, 64, synth_smem(3,6,0,64), stream>>>(yh5, dS5p, tw6p, nullptr, s5p, wIntp, 3, 6, 0, 0, Q3, 1);

  // head
  k_mlp<<<1, 256, 0, stream>>>(s5p, g1, be1, w1, b1, g2, be2, w2, b2, g3, be3, w3, b3, out);
}

// Round 2
// 1091.676 us; speedup vs baseline: 1.7549x; 1.7549x over previous
//
#include <hip/hip_runtime.h>
#include <cmath>
#include <cstring>
#include <vector>

// ============================================================================
// Spherical CNN (s2conv -> 4x so3conv -> integrate -> MLP), MI355X gfx950.
// Round 2: Hermitian-halved fused synthesis, conflict-free twiddle matrices,
// compile-time-sized templated synth kernel, LDS overlays (5 blocks/CU st1).
// ============================================================================

#define DPI 3.14159265358979323846

// ---------------- compile-time sizes ----------------
static constexpr int OQh(int l) { return l*(4*l*l - 1)/3; }   // sum_{l'<l} (2l'+1)^2
static_assert(OQh(30) == 35990, "oq30");
static_assert(OQh(17) == 6545,  "oq17");
static_assert(OQh(9)  == 969,   "oq9");
static_assert(OQh(5)  == 165,   "oq5");
static_assert(OQh(3)  == 35,    "oq3");

// ---------------- workspace layout (bytes) ----------------
static constexpr size_t WS_XF1 = 0;
static constexpr size_t WS_XH1 = WS_XF1 + 32ull*60*30*8;      // [32][60][30] c64
static constexpr size_t WS_KH1 = WS_XH1 + 32ull*900*8;        // [32][900] c64
static constexpr size_t WS_YH1 = WS_KH1 + 1800ull*8;          // [900][2] c64
static constexpr size_t WS_XT2 = WS_YH1 + 64ull*35990*8;      // [64][Q30] c64
static constexpr size_t WS_XH2 = WS_XT2 + 64ull*60*561*8;     // [64][60][33*17]
static constexpr size_t WS_KH2 = WS_XH2 + 64ull*6545*8;
static constexpr size_t WS_YH2 = WS_KH2 + 6545ull*10*8;
static constexpr size_t WS_XT3 = WS_YH2 + 160ull*6545*8;
static constexpr size_t WS_XH3 = WS_XT3 + 160ull*34*153*8;    // [160][34][17*9]
static constexpr size_t WS_KH3 = WS_XH3 + 160ull*969*8;
static constexpr size_t WS_YH3 = WS_KH3 + 969ull*60*8;
static constexpr size_t WS_XT4 = WS_YH3 + 384ull*969*8;
static constexpr size_t WS_XH4 = WS_XT4 + 384ull*18*45*8;     // [384][18][9*5]
static constexpr size_t WS_KH4 = WS_XH4 + 384ull*165*8;
static constexpr size_t WS_YH4 = WS_KH4 + 165ull*336*8;
static constexpr size_t WS_XT5 = WS_YH4 + 896ull*165*8;
static constexpr size_t WS_XH5 = WS_XT5 + 896ull*10*15*8;     // [896][10][5*3]
static constexpr size_t WS_KH5 = WS_XH5 + 896ull*35*8;
static constexpr size_t WS_YH5 = WS_KH5 + 35ull*1792*8;
static constexpr size_t WS_S5P = WS_YH5 + 2048ull*35*8;
static constexpr size_t WS_TOTAL = WS_S5P + 2048ull*6*4;      // ~67 MB

// ---------------- constant-table offsets (filled at dlopen) ----------------
struct ConstOffs {
  size_t A1, A2, A3, A4, A5;        // float offsets (analysis wigner * quadw)
  size_t S1, S2, S3, S4, S5;        // float offsets (synthesis (2l+1)*wigner)
  size_t WInt;                      // float offset (quadw(3)/36, 6 entries)
  size_t nF;
  size_t Fs2, Fso3;                 // float2 offsets (kernel-FT fourier mats)
  size_t Tw60, Tw34, Tw18, Tw10, Tw6; // float2 offsets (cis(2 pi t / N))
  size_t Wn1, Wn2o, Wn3, Wn4, Wn5;  // float2: n-iDFT fold matrices [BQ][N]
  size_t Wg1, Wg2, Wg3, Wg4;        // float2: gamma fwd-DFT matrices [N][KT]
  size_t nC;
};
static ConstOffs CO;
static float*  g_devF = nullptr;
static float2* g_devC = nullptr;

// ============================================================================
// Host: symmetric-tridiagonal eigensolver + Wigner-d builder
// ============================================================================
static void tqli(double* d, double* e, int n, double* z) {
  e[n-1] = 0.0;
  for (int l = 0; l < n; l++) {
    int iter = 0;
    int m;
    do {
      for (m = l; m < n-1; m++) {
        double dd = fabs(d[m]) + fabs(d[m+1]);
        if (fabs(e[m]) <= 1e-300 + 1e-14*dd) break;
      }
      if (m != l) {
        if (iter++ == 80) break;
        double g = (d[l+1]-d[l])/(2.0*e[l]);
        double r = hypot(g, 1.0);
        g = d[m]-d[l]+e[l]/(g + (g >= 0.0 ? fabs(r) : -fabs(r)));
        double s = 1.0, c = 1.0, p = 0.0;
        int i;
        r = 1.0;
        for (i = m-1; i >= l; i--) {
          double f = s*e[i], b = c*e[i];
          r = hypot(f, g);
          e[i+1] = r;
          if (r == 0.0) { d[i+1] -= p; e[m] = 0.0; break; }
          s = f/r; c = g/r;
          g = d[i+1]-p;
          r = (d[i]-g)*s + 2.0*c*b;
          p = s*r;
          d[i+1] = g+p;
          g = c*r-b;
          for (int k = 0; k < n; k++) {
            f = z[(size_t)k*n+i+1];
            z[(size_t)k*n+i+1] = s*z[(size_t)k*n+i] + c*f;
            z[(size_t)k*n+i]   = c*z[(size_t)k*n+i] - s*f;
          }
        }
        if (r == 0.0 && i >= l) continue;
        d[l] -= p; e[l] = g; e[m] = 0.0;
      }
    } while (m != l);
  }
}

struct Builder {
  std::vector<std::vector<double>> V, Lam;
  bool useExpm[30];

  Builder() {
    V.resize(30); Lam.resize(30);
    for (int l = 0; l < 30; l++) {
      int n = 2*l+1;
      std::vector<double> d(n, 0.0), e(n, 0.0), z((size_t)n*n, 0.0);
      for (int i = 0; i < n; i++) z[(size_t)i*n+i] = 1.0;
      for (int i = 0; i+1 < n; i++) {
        double m = (double)i - l;
        e[i] = -0.5*sqrt((double)l*(l+1) - m*(m+1.0));
      }
      if (n > 1) tqli(d.data(), e.data(), n, z.data());
      V[l] = std::move(z); Lam[l] = std::move(d);
    }
    std::vector<double> t((size_t)59*59);
    for (int l = 0; l < 30; l++) {
      useExpm[l] = false;
      if (l == 0) continue;
      int n = 2*l+1;
      eigD(l, 0.77, t.data());
      double corner = pow(cos(0.385), 2.0*l);
      double err = fabs(t[0] - corner) + fabs(t[(size_t)(n-1)*n + (n-1)] - corner);
      double s = 0.0;
      for (int c = 0; c < n; c++) s += t[c]*t[c];
      err += fabs(s - 1.0);
      if (!(err < 1e-8)) useExpm[l] = true;
    }
  }

  void eigD(int l, double beta, double* out) {
    int n = 2*l+1;
    const double* Vp = V[l].data();
    const double* lam = Lam[l].data();
    double ck[64], sk[64];
    for (int k = 0; k < n; k++) { ck[k] = cos(beta*lam[k]); sk[k] = sin(beta*lam[k]); }
    for (int a = 0; a < n; a++) {
      const double* va = Vp + (size_t)a*n;
      for (int c = 0; c < n; c++) {
        const double* vc = Vp + (size_t)c*n;
        int r = ((a - c) % 4 + 4) % 4;
        const double* f = (r & 1) ? sk : ck;
        double s = 0.0;
        for (int k = 0; k < n; k++) s += va[k]*vc[k]*f[k];
        out[(size_t)a*n + c] = (r >= 2) ? -s : s;
      }
    }
  }

  void expmD(int l, double beta, double* out) {
    int n = 2*l+1;
    int s = 0; double bl = fabs(beta)*(double)l + 1e-12;
    while (bl > 0.25) { bl *= 0.5; s++; }
    double sc = ldexp(beta, -s);
    std::vector<double> sup(n > 1 ? n-1 : 0);
    for (int i = 0; i+1 < n; i++) {
      double m = (double)i - l;
      sup[i] = 0.5*sqrt((double)l*(l+1) - m*(m+1.0))*sc;
    }
    std::vector<double> term((size_t)n*n, 0.0), acc((size_t)n*n, 0.0), t2((size_t)n*n);
    for (int i = 0; i < n; i++) { term[(size_t)i*n+i] = 1.0; acc[(size_t)i*n+i] = 1.0; }
    for (int k = 1; k <= 16; k++) {
      for (int r = 0; r < n; r++)
        for (int c = 0; c < n; c++) {
          double v = 0.0;
          if (c > 0)   v += term[(size_t)r*n + c-1]*sup[c-1];
          if (c+1 < n) v -= term[(size_t)r*n + c+1]*sup[c];
          t2[(size_t)r*n+c] = v/(double)k;
        }
      term.swap(t2);
      for (size_t i2 = 0; i2 < (size_t)n*n; i2++) acc[i2] += term[i2];
    }
    for (int t = 0; t < s; t++) {
      for (int r = 0; r < n; r++)
        for (int c = 0; c < n; c++) {
          double v = 0.0;
          for (int k = 0; k < n; k++) v += acc[(size_t)r*n+k]*acc[(size_t)k*n+c];
          t2[(size_t)r*n+c] = v;
        }
      acc.swap(t2);
    }
    std::memcpy(out, acc.data(), sizeof(double)*(size_t)n*n);
  }

  void buildD(int l, double beta, double* out) {
    if (useExpm[l]) expmD(l, beta, out); else eigD(l, beta, out);
  }
};

static std::vector<double> quadw_h(int b) {
  std::vector<double> w(2*b);
  for (int j = 0; j < 2*b; j++) {
    double s = 0;
    for (int k = 0; k < b; k++)
      s += sin(DPI*(2*j+1)*(2*k+1)/(4.0*b))/(double)(2*k+1);
    w[j] = (2.0/b)*sin(DPI*(2*j+1)/(4.0*b))*s;
  }
  return w;
}

static void build_all() {
  size_t o = 0;
  CO.A1 = o; o += 60ull*900;
  CO.A2 = o; o += 60ull*OQh(17);
  CO.A3 = o; o += 34ull*OQh(9);
  CO.A4 = o; o += 18ull*OQh(5);
  CO.A5 = o; o += 10ull*OQh(3);
  CO.S1 = o; o += 60ull*OQh(30);
  CO.S2 = o; o += 34ull*OQh(17);
  CO.S3 = o; o += 18ull*OQh(9);
  CO.S4 = o; o += 10ull*OQh(5);
  CO.S5 = o; o +=  6ull*OQh(3);
  CO.WInt = o; o += 8;
  CO.nF = o;
  size_t c = 0;
  CO.Fs2  = c; c += 6ull*900;
  CO.Fso3 = c; c += 36ull*OQh(17);
  CO.Tw60 = c; c += 60; CO.Tw34 = c; c += 34; CO.Tw18 = c; c += 18;
  CO.Tw10 = c; c += 10; CO.Tw6  = c; c += 6;
  CO.Wn1 = c; c += 30*60; CO.Wn2o = c; c += 17*34; CO.Wn3 = c; c += 9*18;
  CO.Wn4 = c; c += 5*10;  CO.Wn5 = c; c += 3*6;
  CO.Wg1 = c; c += 60*17; CO.Wg2 = c; c += 34*9; CO.Wg3 = c; c += 18*5;
  CO.Wg4 = c; c += 10*3;
  CO.nC = c;

  std::vector<float> HF(CO.nF, 0.f);
  std::vector<float> HC(2*CO.nC, 0.f);

  Builder B;
  auto betas = [](int b){ std::vector<double> v(2*b);
    for (int j = 0; j < 2*b; j++) v[j] = DPI*(2*j+1)/(4.0*b); return v; };
  auto w30 = quadw_h(30), w17 = quadw_h(17), w9 = quadw_h(9), w5 = quadw_h(5), w3 = quadw_h(3);
  std::vector<double> tmp((size_t)59*59);

  { auto bs = betas(30);
    for (int l = 0; l < 30; l++) { int n = 2*l+1;
      for (int j = 0; j < 60; j++) {
        B.buildD(l, bs[j], tmp.data());
        float* dst = HF.data() + CO.S1 + 60ull*OQh(l) + (size_t)j*n*n;
        for (int i2 = 0; i2 < n*n; i2++) dst[i2] = (float)((2*l+1)*tmp[i2]);
        if (l < 17) {
          float* dA = HF.data() + CO.A2 + 60ull*OQh(l) + (size_t)j*n*n;
          for (int i2 = 0; i2 < n*n; i2++) dA[i2] = (float)(tmp[i2]*w30[j]);
        }
        float* dA1 = HF.data() + CO.A1 + 60ull*l*l + (size_t)j*n;
        for (int mi = 0; mi < n; mi++) dA1[mi] = (float)(tmp[(size_t)mi*n + l]*w30[j]);
      } } }
  { auto bs = betas(17);
    for (int l = 0; l < 17; l++) { int n = 2*l+1;
      for (int j = 0; j < 34; j++) {
        B.buildD(l, bs[j], tmp.data());
        float* dst = HF.data() + CO.S2 + 34ull*OQh(l) + (size_t)j*n*n;
        for (int i2 = 0; i2 < n*n; i2++) dst[i2] = (float)((2*l+1)*tmp[i2]);
        if (l < 9) {
          float* dA = HF.data() + CO.A3 + 34ull*OQh(l) + (size_t)j*n*n;
          for (int i2 = 0; i2 < n*n; i2++) dA[i2] = (float)(tmp[i2]*w17[j]);
        } } } }
  { auto bs = betas(9);
    for (int l = 0; l < 9; l++) { int n = 2*l+1;
      for (int j = 0; j < 18; j++) {
        B.buildD(l, bs[j], tmp.data());
        float* dst = HF.data() + CO.S3 + 18ull*OQh(l) + (size_t)j*n*n;
        for (int i2 = 0; i2 < n*n; i2++) dst[i2] = (float)((2*l+1)*tmp[i2]);
        if (l < 5) {
          float* dA = HF.data() + CO.A4 + 18ull*OQh(l) + (size_t)j*n*n;
          for (int i2 = 0; i2 < n*n; i2++) dA[i2] = (float)(tmp[i2]*w9[j]);
        } } } }
  { auto bs = betas(5);
    for (int l = 0; l < 5; l++) { int n = 2*l+1;
      for (int j = 0; j < 10; j++) {
        B.buildD(l, bs[j], tmp.data());
        float* dst = HF.data() + CO.S4 + 10ull*OQh(l) + (size_t)j*n*n;
        for (int i2 = 0; i2 < n*n; i2++) dst[i2] = (float)((2*l+1)*tmp[i2]);
        if (l < 3) {
          float* dA = HF.data() + CO.A5 + 10ull*OQh(l) + (size_t)j*n*n;
          for (int i2 = 0; i2 < n*n; i2++) dA[i2] = (float)(tmp[i2]*w5[j]);
        } } } }
  { auto bs = betas(3);
    for (int l = 0; l < 3; l++) { int n = 2*l+1;
      for (int j = 0; j < 6; j++) {
        B.buildD(l, bs[j], tmp.data());
        float* dst = HF.data() + CO.S5 + 6ull*OQh(l) + (size_t)j*n*n;
        for (int i2 = 0; i2 < n*n; i2++) dst[i2] = (float)((2*l+1)*tmp[i2]);
      } } }
  { double beta = DPI/16.0;
    for (int l = 0; l < 30; l++) { int n = 2*l+1;
      B.buildD(l, beta, tmp.data());
      for (int p = 0; p < 6; p++) {
        double al = 2.0*DPI*p/6.0;
        for (int mi = 0; mi < n; mi++) {
          double ph = al*(double)(mi - l);
          double dr = tmp[(size_t)mi*n + l];
          size_t off = CO.Fs2 + 6ull*l*l + (size_t)p*n + mi;
          HC[2*off]   = (float)(dr*cos(ph));
          HC[2*off+1] = (float)(dr*sin(ph));
        } }
      if (l < 17) {
        for (int p = 0; p < 36; p++) {
          double al = 2.0*DPI*(p/6)/6.0, ga = 2.0*DPI*(p%6)/6.0;
          for (int mi = 0; mi < n; mi++)
            for (int ni = 0; ni < n; ni++) {
              double ph = al*(double)(mi - l) + ga*(double)(ni - l);
              double dr = tmp[(size_t)mi*n + ni];
              size_t off = CO.Fso3 + 36ull*OQh(l) + (size_t)p*n*n + (size_t)mi*n + ni;
              HC[2*off]   = (float)(dr*cos(ph));
              HC[2*off+1] = (float)(dr*sin(ph));
            } } } } }
  auto fillTw = [&](size_t ofs, int N){
    for (int t = 0; t < N; t++) {
      HC[2*(ofs+t)]   = (float)cos(2.0*DPI*t/N);
      HC[2*(ofs+t)+1] = (float)sin(2.0*DPI*t/N);
    } };
  fillTw(CO.Tw60, 60); fillTw(CO.Tw34, 34); fillTw(CO.Tw18, 18);
  fillTw(CO.Tw10, 10); fillTw(CO.Tw6, 6);
  // n-iDFT Hermitian-fold matrices: (fac*cos(2pi n c/N), fac*sin(2pi n c/N))
  auto fillWn = [&](size_t ofs, int BQ, int N){
    for (int n = 0; n < BQ; n++)
      for (int cc2 = 0; cc2 < N; cc2++) {
        double f = (n == 0) ? 1.0 : 2.0;
        HC[2*(ofs + (size_t)n*N + cc2)]   = (float)(f*cos(2.0*DPI*n*cc2/N));
        HC[2*(ofs + (size_t)n*N + cc2)+1] = (float)(f*sin(2.0*DPI*n*cc2/N));
      } };
  // gamma fwd-DFT matrices [c][k]: cis(-2pi k c / N)
  auto fillWg = [&](size_t ofs, int N, int KT){
    for (int cc2 = 0; cc2 < N; cc2++)
      for (int k = 0; k < KT; k++) {
        HC[2*(ofs + (size_t)cc2*KT + k)]   = (float)cos(2.0*DPI*k*cc2/N);
        HC[2*(ofs + (size_t)cc2*KT + k)+1] = (float)(-sin(2.0*DPI*k*cc2/N));
      } };
  fillWn(CO.Wn1, 30, 60); fillWn(CO.Wn2o, 17, 34); fillWn(CO.Wn3, 9, 18);
  fillWn(CO.Wn4, 5, 10);  fillWn(CO.Wn5, 3, 6);
  fillWg(CO.Wg1, 60, 17); fillWg(CO.Wg2, 34, 9); fillWg(CO.Wg3, 18, 5);
  fillWg(CO.Wg4, 10, 3);
  for (int j = 0; j < 6; j++) HF[CO.WInt + j] = (float)(w3[j]/36.0);

  size_t fb = CO.nF * sizeof(float);
  size_t fbA = (fb + 255) & ~(size_t)255;
  size_t cb = CO.nC * sizeof(float2);
  void* base = nullptr;
  if (hipMalloc(&base, fbA + cb) != hipSuccess || !base) return;
  if (hipMemcpy(base, HF.data(), fb, hipMemcpyHostToDevice) != hipSuccess) return;
  if (hipMemcpy((char*)base + fbA, HC.data(), cb, hipMemcpyHostToDevice) != hipSuccess) return;
  (void)hipDeviceSynchronize();
  g_devF = (float*)base;
  g_devC = (float2*)((char*)base + fbA);
}
namespace { struct InitOnce { InitOnce(){ build_all(); } } g_once; }

// ============================================================================
// Device helpers
// ============================================================================
__device__ __forceinline__ int OQ(int l) { return l*(4*l*l - 1)/3; }
__device__ __forceinline__ int lFromQ(int q, int L) {
  int l = 0;
  while (l+1 < L && OQ(l+1) <= q) l++;
  return l;
}
__device__ __forceinline__ int lsq(int q) {
  int l = (int)sqrtf((float)q);
  while ((l+1)*(l+1) <= q) l++;
  while (l*l > q) l--;
  return l;
}

// ---------------- kernel FT: s2 ----------------
__global__ __launch_bounds__(256) void k_kh_s2(
    const float* __restrict__ ks2, const float2* __restrict__ F, float2* __restrict__ kh)
{
  int id = blockIdx.x*blockDim.x + threadIdx.x;
  if (id >= 1800) return;
  int q = id >> 1, o = id & 1;
  int l = lsq(q); int W = 2*l+1; int mi = q - l*l;
  const float2* Fb = F + 6ull*l*l;
  float ax = 0.f, ay = 0.f;
  for (int p = 0; p < 6; p++) {
    float kv = ks2[o*6 + p];
    float2 f = Fb[p*W + mi];
    ax += kv*f.x; ay += kv*f.y;
  }
  kh[(size_t)q*2 + o] = make_float2(ax, ay);
}

// ---------------- kernel FT: so3 ----------------
__global__ __launch_bounds__(256) void k_kh_so3(
    const float* __restrict__ kk, const float2* __restrict__ F,
    float2* __restrict__ kh, int L, int fi, int fo)
{
  int id = blockIdx.x*blockDim.x + threadIdx.x;
  int ff = fi*fo;
  if (id >= OQ(L)*ff) return;
  int q = id / ff, r = id - q*ff;
  int i = r / fo, o = r - i*fo;
  int l = lFromQ(q, L); int W = 2*l+1; int W21 = W*W;
  int rem = q - OQ(l);
  const float2* Fb = F + 36ull*OQ(l) + rem;
  const float* kb = kk + (size_t)(i*fo + o)*36;
  float ax = 0.f, ay = 0.f;
  for (int p = 0; p < 36; p++) {
    float kv = kb[p];
    float2 f = Fb[(size_t)p*W21];
    ax += kv*f.x; ay += kv*f.y;
  }
  kh[(size_t)q*ff + r] = make_float2(ax, ay);
}

// ---------------- stage-1 analysis: alpha DFT (real input, m=0..29) --------
__global__ __launch_bounds__(64) void k_s1_fftA(
    const float* __restrict__ x, const float2* __restrict__ tw, float2* __restrict__ XF1)
{
  __shared__ float row[60];
  int b = blockIdx.x / 60, j = blockIdx.x - b*60;
  int t = threadIdx.x;
  if (t < 60) row[t] = x[((size_t)b*60 + j)*60 + t];
  __syncthreads();
  if (t < 30) {
    float ax = 0.f, ay = 0.f;
    int ti = 0;
    for (int a = 0; a < 60; a++) {
      float2 w = tw[ti];
      ax += row[a]*w.x; ay -= row[a]*w.y;
      ti += t; if (ti >= 60) ti -= 60;
    }
    XF1[((size_t)b*60 + j)*30 + t] = make_float2(ax, ay);
  }
}

// ---------------- stage-1 beta contraction ----------------
__global__ __launch_bounds__(256) void k_s1_coef(
    const float2* __restrict__ XF1, const float* __restrict__ dA1, float2* __restrict__ xh1)
{
  int id = blockIdx.x*blockDim.x + threadIdx.x;
  if (id >= 32*900) return;
  int b = id / 900, q = id - b*900;
  int l = lsq(q); int W = 2*l+1; int mi = q - l*l; int m = mi - l;
  const float* dp = dA1 + 60ull*l*l + mi;
  const float2* xb = XF1 + (size_t)b*60*30;
  int ma = m >= 0 ? m : -m;
  float sg = m >= 0 ? 1.f : -1.f;
  float ax = 0.f, ay = 0.f;
  for (int j = 0; j < 60; j++) {
    float2 xf = xb[j*30 + ma];
    float d = dp[(size_t)j*W];
    ax += d*xf.x; ay += sg*d*xf.y;
  }
  xh1[id] = make_float2(ax, ay);
}

// ---------------- stage-1 spectral product ----------------
__global__ __launch_bounds__(256) void k_s1_yh(
    const float2* __restrict__ xh1, const float2* __restrict__ kh1, float2* __restrict__ yh1)
{
  int id = blockIdx.x*blockDim.x + threadIdx.x;
  if (id >= 64*35990) return;
  int bo = id / 35990, q = id - bo*35990;
  int b = bo >> 1, o = bo & 1;
  int l = lFromQ(q, 30); int W = 2*l+1;
  int rem = q - OQ(l); int mi = rem / W, ni = rem - mi*W;
  float2 xv = xh1[(size_t)b*900 + l*l + mi];
  float2 kv = kh1[(size_t)(l*l + ni)*2 + o];
  yh1[id] = make_float2(xv.x*kv.x + xv.y*kv.y, xv.y*kv.x - xv.x*kv.y);
}

// ---------------- generic spectral product for so3 stages ------------------
__global__ __launch_bounds__(256) void k_yh(
    const float2* __restrict__ xh, const float2* __restrict__ kh,
    float2* __restrict__ yh, int L, int fi, int fo, int Qtot)
{
  int id = blockIdx.x*blockDim.x + threadIdx.x;
  if (id >= 32*fo*Qtot) return;
  int bo = id / Qtot, q = id - bo*Qtot;
  int b = bo / fo, o = bo - b*fo;
  int l = lFromQ(q, L); int W = 2*l+1;
  int rem = q - OQ(l); int mi = rem / W, ni = rem - mi*W;
  int ff = fi*fo;
  const float2* xb = xh + ((size_t)b*fi)*Qtot + OQ(l) + mi*W;
  const float2* kb = kh + ((size_t)(OQ(l) + ni*W))*ff + o;
  float ax = 0.f, ay = 0.f;
  for (int i = 0; i < fi; i++) {
    const float2* xrow = xb + (size_t)i*Qtot;
    const float2* krow = kb + (size_t)i*fo;
    for (int k = 0; k < W; k++) {
      float2 xv = xrow[k];
      float2 kv = krow[(size_t)k*ff];
      ax += xv.x*kv.x + xv.y*kv.y;
      ay += xv.y*kv.x - xv.x*kv.y;
    }
  }
  yh[id] = make_float2(ax, ay);
}

// ---------------- generic beta contraction for so3 stages ------------------
__global__ __launch_bounds__(256) void k_coef(
    const float2* __restrict__ xt, const float* __restrict__ dA,
    float2* __restrict__ xh, int L, int nj, int KT, int MT, int Qtot, int nbi)
{
  int id = blockIdx.x*blockDim.x + threadIdx.x;
  if (id >= nbi*Qtot) return;
  int bi = id / Qtot, q = id - bi*Qtot;
  int l = lFromQ(q, L); int W = 2*l+1; int W21 = W*W;
  int rem = q - OQ(l); int mi = rem / W, ki = rem - mi*W;
  int m = mi - l, ks = ki - l;
  const float* dAp = dA + (size_t)nj*OQ(l) + rem;
  int MTKT = MT*KT;
  int pidx; float sgn;
  if (ks >= 0) { pidx = (m + (KT-1))*KT + ks;  sgn =  1.f; }
  else         { pidx = (-m + (KT-1))*KT - ks; sgn = -1.f; }
  const float2* xb = xt + (size_t)bi*nj*MTKT + pidx;
  float ax = 0.f, ay = 0.f;
  for (int j = 0; j < nj; j++) {
    float2 xv = xb[(size_t)j*MTKT];
    float d = dAp[(size_t)j*W21];
    ax += d*xv.x; ay += sgn*d*xv.y;
  }
  xh[id] = make_float2(ax, ay);
}

// ============================================================================
// Fused synthesis v2: Hermitian-halved scatter -> iDFT2 -> ReLU -> fwd DFT2.
// One block per (batch*channel, beta_j) slab; all sizes compile-time.
// LDS overlays: region A = P[W2][BQ] then S[N][N]; region B = Tm[N][BQ] then
// U[N][KT] (or reduction scratch). Twiddle reads are lane-uniform; the
// lane-varying DFT matrices (Wn2, Wg) stream coalesced from global (L1-hot).
// ============================================================================
template<int BQ, int N, int KT, int MT, int INTEG, int NPAIR, int TPB>
__global__ __launch_bounds__(TPB) void k_synth2(
    const float2* __restrict__ yh, const float* __restrict__ dS,
    const float2* __restrict__ twN, const float2* __restrict__ Wn2,
    const float2* __restrict__ Wg, float2* __restrict__ xt,
    float* __restrict__ s5p, const float* __restrict__ wInt)
{
  constexpr int W2 = 2*BQ - 1;
  constexpr int QT = BQ*(4*BQ*BQ - 1)/3;
  constexpr int SZA = (((W2*BQ*8 > N*N*4) ? W2*BQ*8 : N*N*4) + 15) & ~15;
  constexpr int SZB0 = (N*BQ*8 > N*KT*8) ? N*BQ*8 : N*KT*8;
  constexpr int SZB1 = (SZB0 > TPB*4) ? SZB0 : TPB*4;
  constexpr int SZB = (SZB1 + 15) & ~15;
  __shared__ __align__(16) char smem[SZA + SZB + N*8];
  float2* P   = (float2*)smem;              // [W2][BQ]   (n >= 0 half-plane)
  float*  S   = (float*)smem;               // [N][N]     (overlay after P dead)
  float2* Tm  = (float2*)(smem + SZA);      // [N][BQ]
  float2* U   = (float2*)(smem + SZA);      // [N][KT]    (overlay after Tm dead)
  float*  red = (float*)(smem + SZA);
  float2* twl = (float2*)(smem + SZA + SZB);

  const int tid = threadIdx.x;
  int bidx = blockIdx.x, nwg = gridDim.x;
  int per = nwg >> 3;
  int swz = (bidx & 7)*per + (bidx >> 3);   // bijective: grids are %8==0
  int bo = swz / N, j = swz - bo*N;

  for (int t = tid; t < N; t += TPB) twl[t] = twN[t];
  __syncthreads();

  // --- phase 1: Wigner scatter, n >= 0 half (P[-m][-n] = conj(P[m][n]))
  const float2* yhb = yh + (size_t)bo*QT;
  for (int idx = tid; idx < W2*BQ; idx += TPB) {
    int pm = idx / BQ, n = idx - pm*BQ;
    int m = pm - (BQ-1);
    int am = m < 0 ? -m : m;
    int lmin = am > n ? am : n;
    int base = lmin*(4*lmin*lmin - 1)/3;
    float ax = 0.f, ay = 0.f;
    for (int l = lmin; l < BQ; l++) {
      int Wl = 2*l+1;
      float2 y = yhb[base + (m+l)*Wl + (n+l)];
      float d = dS[(size_t)N*base + (size_t)j*Wl*Wl + (m+l)*Wl + (n+l)];
      ax += d*y.x; ay += d*y.y;
      base += Wl*Wl;
    }
    P[idx] = make_float2(ax, ay);
  }
  __syncthreads();

  // --- phase 2: iDFT along m (alpha), n >= 0 columns only
  if (NPAIR == 2) {
    constexpr int NG = BQ/2;
    const float4* P4 = (const float4*)P;
    float4* Tm4 = (float4*)Tm;
    for (int idx = tid; idx < (N/2)*NG; idx += TPB) {
      int ag = idx / NG, ng = idx - ag*NG;
      int a0 = 2*ag, a1 = a0 + 1;
      int t0 = (N - (a0*(BQ-1)) % N) % N;
      int t1 = (N - (a1*(BQ-1)) % N) % N;
      float4 A0 = {0,0,0,0}, A1 = {0,0,0,0};
      for (int pm = 0; pm < W2; pm++) {
        float4 p = P4[pm*NG + ng];
        float2 w0 = twl[t0], w1 = twl[t1];
        A0.x += p.x*w0.x - p.y*w0.y; A0.y += p.x*w0.y + p.y*w0.x;
        A0.z += p.z*w0.x - p.w*w0.y; A0.w += p.z*w0.y + p.w*w0.x;
        A1.x += p.x*w1.x - p.y*w1.y; A1.y += p.x*w1.y + p.y*w1.x;
        A1.z += p.z*w1.x - p.w*w1.y; A1.w += p.z*w1.y + p.w*w1.x;
        t0 += a0; if (t0 >= N) t0 -= N;
        t1 += a1; if (t1 >= N) t1 -= N;
      }
      Tm4[a0*NG + ng] = A0;
      Tm4[a1*NG + ng] = A1;
    }
  } else {
    for (int idx = tid; idx < (N/2)*BQ; idx += TPB) {
      int ag = idx / BQ, n = idx - ag*BQ;
      int a0 = 2*ag, a1 = a0 + 1;
      int t0 = (N - (a0*(BQ-1)) % N) % N;
      int t1 = (N - (a1*(BQ-1)) % N) % N;
      float2 A0 = {0,0}, A1 = {0,0};
      for (int pm = 0; pm < W2; pm++) {
        float2 p = P[pm*BQ + n];
        float2 w0 = twl[t0], w1 = twl[t1];
        A0.x += p.x*w0.x - p.y*w0.y; A0.y += p.x*w0.y + p.y*w0.x;
        A1.x += p.x*w1.x - p.y*w1.y; A1.y += p.x*w1.y + p.y*w1.x;
        t0 += a0; if (t0 >= N) t0 -= N;
        t1 += a1; if (t1 >= N) t1 -= N;
      }
      Tm[a0*BQ + n] = A0;
      Tm[a1*BQ + n] = A1;
    }
  }
  __syncthreads();

  // --- phase 3: real iDFT along n (gamma) via Hermitian fold, + ReLU
  {
    constexpr int CG = N/2;
    const float4* WnR = (const float4*)Wn2;   // [BQ][CG] of (c0-pair)
    for (int idx = tid; idx < N*CG; idx += TPB) {
      int a = idx / CG, cg = idx - a*CG;
      float s0 = 0.f, s1 = 0.f;
      const float2* TmA = Tm + a*BQ;
      for (int n = 0; n < BQ; n++) {
        float2 T = TmA[n];
        float4 w = WnR[n*CG + cg];
        s0 += T.x*w.x - T.y*w.y;
        s1 += T.x*w.z - T.y*w.w;
      }
      s0 = fmaxf(s0, 0.f); s1 = fmaxf(s1, 0.f);
      *(float2*)&S[a*N + 2*cg] = make_float2(s0, s1);
    }
  }
  __syncthreads();

  if constexpr (!INTEG) {
    // --- phase 4: forward DFT along gamma, k = 0..KT-1 (row pairs)
    for (int idx = tid; idx < (N/2)*KT; idx += TPB) {
      int ag = idx / KT, k = idx - ag*KT;
      int a0 = 2*ag, a1 = a0 + 1;
      float u0x=0.f,u0y=0.f,u1x=0.f,u1y=0.f;
      const float* S0 = S + a0*N;
      const float* S1 = S + a1*N;
      for (int c = 0; c < N; c++) {
        float2 w = Wg[c*KT + k];
        u0x += S0[c]*w.x; u0y += S0[c]*w.y;
        u1x += S1[c]*w.x; u1y += S1[c]*w.y;
      }
      U[a0*KT + k] = make_float2(u0x, u0y);
      U[a1*KT + k] = make_float2(u1x, u1y);
    }
    __syncthreads();

    // --- phase 5: forward DFT along alpha, m = -(KT-1)..KT-1
    float2* xtb = xt + ((size_t)bo*N + j)*(MT*KT);
    for (int idx = tid; idx < MT*KT; idx += TPB) {
      int pm2 = idx / KT, k = idx - pm2*KT;
      int m = pm2 - (KT-1);
      float ax = 0.f, ay = 0.f;
      int t = 0;
      for (int a = 0; a < N; a++) {
        float2 u = U[a*KT + k];
        float2 w = twl[t];
        ax += u.x*w.x + u.y*w.y;
        ay += u.y*w.x - u.x*w.y;
        t += m; if (t < 0) t += N; else if (t >= N) t -= N;
      }
      xtb[idx] = make_float2(ax, ay);
    }
  } else {
    // --- integrate: weighted full-sphere sum of S
    float part = 0.f;
    for (int idx = tid; idx < N*N; idx += TPB) part += S[idx];
    red[tid] = part;
    __syncthreads();
    for (int off2 = TPB >> 1; off2 > 0; off2 >>= 1) {
      if (tid < off2) red[tid] += red[tid + off2];
      __syncthreads();
    }
    if (tid == 0) s5p[bo*N + j] = red[0]*wInt[j];
  }
}

// ---------------- head: integrate-reduce + 3x (batchnorm, linear) ----------
__global__ __launch_bounds__(256) void k_mlp(
    const float* __restrict__ s5p,
    const float* __restrict__ g1, const float* __restrict__ be1,
    const float* __restrict__ w1, const float* __restrict__ b1,
    const float* __restrict__ g2, const float* __restrict__ be2,
    const float* __restrict__ w2, const float* __restrict__ b2,
    const float* __restrict__ g3, const float* __restrict__ be3,
    const float* __restrict__ w3, const float* __restrict__ b3,
    float* __restrict__ out)
{
  __shared__ float A[2048], Bs[2048], C[1024], mu[64], iv[64];
  int tid = threadIdx.x;
  for (int idx = tid; idx < 2048; idx += 256) {
    float s = 0.f;
    #pragma unroll
    for (int j = 0; j < 6; j++) s += s5p[idx*6 + j];
    A[idx] = s;
  }
  __syncthreads();
  if (tid < 64) {
    float m = 0.f; for (int b = 0; b < 32; b++) m += A[b*64 + tid]; m *= (1.f/32);
    float v = 0.f; for (int b = 0; b < 32; b++) { float d = A[b*64+tid]-m; v += d*d; } v *= (1.f/32);
    mu[tid] = m; iv[tid] = rsqrtf(v + 1e-5f)*g1[tid];
  }
  __syncthreads();
  for (int idx = tid; idx < 2048; idx += 256) {
    int f = idx & 63;
    A[idx] = (A[idx]-mu[f])*iv[f] + be1[f];
  }
  __syncthreads();
  for (int idx = tid; idx < 2048; idx += 256) {
    int b = idx >> 6, fo = idx & 63;
    float s = b1[fo];
    for (int f = 0; f < 64; f++) s += A[b*64+f]*w1[f*64+fo];
    Bs[idx] = fmaxf(s, 0.f);
  }
  __syncthreads();
  if (tid < 64) {
    float m = 0.f; for (int b = 0; b < 32; b++) m += Bs[b*64+tid]; m *= (1.f/32);
    float v = 0.f; for (int b = 0; b < 32; b++) { float d = Bs[b*64+tid]-m; v += d*d; } v *= (1.f/32);
    mu[tid] = m; iv[tid] = rsqrtf(v + 1e-5f)*g2[tid];
  }
  __syncthreads();
  for (int idx = tid; idx < 2048; idx += 256) {
    int f = idx & 63;
    Bs[idx] = (Bs[idx]-mu[f])*iv[f] + be2[f];
  }
  __syncthreads();
  for (int idx = tid; idx < 1024; idx += 256) {
    int b = idx >> 5, fo = idx & 31;
    float s = b2[fo];
    for (int f = 0; f < 64; f++) s += Bs[b*64+f]*w2[f*32+fo];
    C[idx] = fmaxf(s, 0.f);
  }
  __syncthreads();
  if (tid < 32) {
    float m = 0.f; for (int b = 0; b < 32; b++) m += C[b*32+tid]; m *= (1.f/32);
    float v = 0.f; for (int b = 0; b < 32; b++) { float d = C[b*32+tid]-m; v += d*d; } v *= (1.f/32);
    mu[tid] = m; iv[tid] = rsqrtf(v + 1e-5f)*g3[tid];
  }
  __syncthreads();
  for (int idx = tid; idx < 1024; idx += 256) {
    int f = idx & 31;
    C[idx] = (C[idx]-mu[f])*iv[f] + be3[f];
  }
  __syncthreads();
  for (int idx = tid; idx < 320; idx += 256) {
    int b = idx/10, cc = idx - b*10;
    float s = b3[cc];
    for (int f = 0; f < 32; f++) s += C[b*32+f]*w3[f*10+cc];
    out[idx] = s;
  }
}

// ============================================================================
// launch
// ============================================================================
static inline int cdiv_h(int a, int b) { return (a + b - 1)/b; }

extern "C" void kernel_launch(void* const* d_in, const int* in_sizes, int n_in,
                              void* d_out, int out_size, void* d_ws, size_t ws_size,
                              hipStream_t stream) {
  (void)in_sizes; (void)n_in; (void)out_size;
  if (!g_devF || !g_devC || ws_size < WS_TOTAL) return;

  const float* x    = (const float*)d_in[0];
  const float* ks2  = (const float*)d_in[1];
  const float* k1   = (const float*)d_in[2];
  const float* k2   = (const float*)d_in[3];
  const float* k3   = (const float*)d_in[4];
  const float* k4   = (const float*)d_in[5];
  const float* g1   = (const float*)d_in[6],  *be1 = (const float*)d_in[7];
  const float* w1   = (const float*)d_in[8],  *b1  = (const float*)d_in[9];
  const float* g2   = (const float*)d_in[10], *be2 = (const float*)d_in[11];
  const float* w2   = (const float*)d_in[12], *b2  = (const float*)d_in[13];
  const float* g3   = (const float*)d_in[14], *be3 = (const float*)d_in[15];
  const float* w3   = (const float*)d_in[16], *b3  = (const float*)d_in[17];
  float* out = (float*)d_out;
  char* ws = (char*)d_ws;

  float2* XF1 = (float2*)(ws + WS_XF1);
  float2* xh1 = (float2*)(ws + WS_XH1);
  float2* kh1 = (float2*)(ws + WS_KH1);
  float2* yh1 = (float2*)(ws + WS_YH1);
  float2* xt2 = (float2*)(ws + WS_XT2);
  float2* xh2 = (float2*)(ws + WS_XH2);
  float2* kh2 = (float2*)(ws + WS_KH2);
  float2* yh2 = (float2*)(ws + WS_YH2);
  float2* xt3 = (float2*)(ws + WS_XT3);
  float2* xh3 = (float2*)(ws + WS_XH3);
  float2* kh3 = (float2*)(ws + WS_KH3);
  float2* yh3 = (float2*)(ws + WS_YH3);
  float2* xt4 = (float2*)(ws + WS_XT4);
  float2* xh4 = (float2*)(ws + WS_XH4);
  float2* kh4 = (float2*)(ws + WS_KH4);
  float2* yh4 = (float2*)(ws + WS_YH4);
  float2* xt5 = (float2*)(ws + WS_XT5);
  float2* xh5 = (float2*)(ws + WS_XH5);
  float2* kh5 = (float2*)(ws + WS_KH5);
  float2* yh5 = (float2*)(ws + WS_YH5);
  float*  s5p = (float*) (ws + WS_S5P);

  const float* dA1p = g_devF + CO.A1; const float* dA2p = g_devF + CO.A2;
  const float* dA3p = g_devF + CO.A3; const float* dA4p = g_devF + CO.A4;
  const float* dA5p = g_devF + CO.A5;
  const float* dS1p = g_devF + CO.S1; const float* dS2p = g_devF + CO.S2;
  const float* dS3p = g_devF + CO.S3; const float* dS4p = g_devF + CO.S4;
  const float* dS5p = g_devF + CO.S5;
  const float* wIntp = g_devF + CO.WInt;
  const float2* Fs2p  = g_devC + CO.Fs2;
  const float2* Fso3p = g_devC + CO.Fso3;
  const float2* tw60p = g_devC + CO.Tw60; const float2* tw34p = g_devC + CO.Tw34;
  const float2* tw18p = g_devC + CO.Tw18; const float2* tw10p = g_devC + CO.Tw10;
  const float2* tw6p  = g_devC + CO.Tw6;
  const float2* Wn1p = g_devC + CO.Wn1; const float2* Wn2p = g_devC + CO.Wn2o;
  const float2* Wn3p = g_devC + CO.Wn3; const float2* Wn4p = g_devC + CO.Wn4;
  const float2* Wn5p = g_devC + CO.Wn5;
  const float2* Wg1p = g_devC + CO.Wg1; const float2* Wg2p = g_devC + CO.Wg2;
  const float2* Wg3p = g_devC + CO.Wg3; const float2* Wg4p = g_devC + CO.Wg4;

  constexpr int Q30 = OQh(30), Q17 = OQh(17), Q9 = OQh(9), Q5 = OQh(5), Q3 = OQh(3);

  // kernel FTs
  k_kh_s2 <<<cdiv_h(1800,256),      256, 0, stream>>>(ks2, Fs2p,  kh1);
  k_kh_so3<<<cdiv_h(Q17*10,256),    256, 0, stream>>>(k1, Fso3p, kh2, 17, 2, 5);
  k_kh_so3<<<cdiv_h(Q9*60,256),     256, 0, stream>>>(k2, Fso3p, kh3, 9, 5, 12);
  k_kh_so3<<<cdiv_h(Q5*336,256),    256, 0, stream>>>(k3, Fso3p, kh4, 5, 12, 28);
  k_kh_so3<<<cdiv_h(Q3*1792,256),   256, 0, stream>>>(k4, Fso3p, kh5, 3, 28, 64);

  // stage 1: s2 analysis + spectral product
  k_s1_fftA<<<32*60, 64, 0, stream>>>(x, tw60p, XF1);
  k_s1_coef<<<cdiv_h(32*900,256), 256, 0, stream>>>(XF1, dA1p, xh1);
  k_s1_yh  <<<cdiv_h(64*Q30,256), 256, 0, stream>>>(xh1, kh1, yh1);

  // stage boundaries: fused synth (Hermitian-halved) + coef + yh
  k_synth2<30,60,17,33,0,2,256><<<64*60,  256, 0, stream>>>(yh1, dS1p, tw60p, Wn1p, Wg1p, xt2, nullptr, nullptr);
  k_coef <<<cdiv_h(64*Q17,256),  256, 0, stream>>>(xt2, dA2p, xh2, 17, 60, 17, 33, Q17, 64);
  k_yh   <<<cdiv_h(160*Q17,256), 256, 0, stream>>>(xh2, kh2, yh2, 17, 2, 5, Q17);

  k_synth2<17,34,9,17,0,1,128><<<160*34, 128, 0, stream>>>(yh2, dS2p, tw34p, Wn2p, Wg2p, xt3, nullptr, nullptr);
  k_coef <<<cdiv_h(160*Q9,256),  256, 0, stream>>>(xt3, dA3p, xh3, 9, 34, 9, 17, Q9, 160);
  k_yh   <<<cdiv_h(384*Q9,256),  256, 0, stream>>>(xh3, kh3, yh3, 9, 5, 12, Q9);

  k_synth2<9,18,5,9,0,1,128><<<384*18, 128, 0, stream>>>(yh3, dS3p, tw18p, Wn3p, Wg3p, xt4, nullptr, nullptr);
  k_coef <<<cdiv_h(384*Q5,256),  256, 0, stream>>>(xt4, dA4p, xh4, 5, 18, 5, 9, Q5, 384);
  k_yh   <<<cdiv_h(896*Q5,256),  256, 0, stream>>>(xh4, kh4, yh4, 5, 12, 28, Q5);

  k_synth2<5,10,3,5,0,1,64><<<896*10, 64, 0, stream>>>(yh4, dS4p, tw10p, Wn4p, Wg4p, xt5, nullptr, nullptr);
  k_coef <<<cdiv_h(896*Q3,256),  256, 0, stream>>>(xt5, dA5p, xh5, 3, 10, 3, 5, Q3, 896);
  k_yh   <<<cdiv_h(2048*Q3,256), 256, 0, stream>>>(xh5, kh5, yh5, 3, 28, 64, Q3);

  // final synthesis fused with so3_integrate
  k_synth2<3,6,3,5,1,1,64><<<2048*6, 64, 0, stream>>>(yh5, dS5p, tw6p, Wn5p, nullptr, nullptr, s5p, wIntp);

  // head
  k_mlp<<<1, 256, 0, stream>>>(s5p, g1, be1, w1, b1, g2, be2, w2, b2, g3, be3, w3, b3, out);
}

// Round 3
// 936.351 us; speedup vs baseline: 2.0460x; 1.1659x over previous
//
#include <hip/hip_runtime.h>
#include <cmath>
#include <cstring>
#include <vector>

// ============================================================================
// Spherical CNN (s2conv -> 4x so3conv -> integrate -> MLP), MI355X gfx950.
// Round 3: radix-2 split DFT phases + register rotator recurrences in the
// fused synthesis (stages 1-3); phases fused (Ssum/Udif in epilogues).
// ============================================================================

#define DPI 3.14159265358979323846

// ---------------- compile-time sizes ----------------
static constexpr int OQh(int l) { return l*(4*l*l - 1)/3; }   // sum_{l'<l} (2l'+1)^2
static_assert(OQh(30) == 35990, "oq30");
static_assert(OQh(17) == 6545,  "oq17");
static_assert(OQh(9)  == 969,   "oq9");
static_assert(OQh(5)  == 165,   "oq5");
static_assert(OQh(3)  == 35,    "oq3");

// ---------------- workspace layout (bytes) ----------------
static constexpr size_t WS_XF1 = 0;
static constexpr size_t WS_XH1 = WS_XF1 + 32ull*60*30*8;
static constexpr size_t WS_KH1 = WS_XH1 + 32ull*900*8;
static constexpr size_t WS_YH1 = WS_KH1 + 1800ull*8;
static constexpr size_t WS_XT2 = WS_YH1 + 64ull*35990*8;
static constexpr size_t WS_XH2 = WS_XT2 + 64ull*60*561*8;
static constexpr size_t WS_KH2 = WS_XH2 + 64ull*6545*8;
static constexpr size_t WS_YH2 = WS_KH2 + 6545ull*10*8;
static constexpr size_t WS_XT3 = WS_YH2 + 160ull*6545*8;
static constexpr size_t WS_XH3 = WS_XT3 + 160ull*34*153*8;
static constexpr size_t WS_KH3 = WS_XH3 + 160ull*969*8;
static constexpr size_t WS_YH3 = WS_KH3 + 969ull*60*8;
static constexpr size_t WS_XT4 = WS_YH3 + 384ull*969*8;
static constexpr size_t WS_XH4 = WS_XT4 + 384ull*18*45*8;
static constexpr size_t WS_KH4 = WS_XH4 + 384ull*165*8;
static constexpr size_t WS_YH4 = WS_KH4 + 165ull*336*8;
static constexpr size_t WS_XT5 = WS_YH4 + 896ull*165*8;
static constexpr size_t WS_XH5 = WS_XT5 + 896ull*10*15*8;
static constexpr size_t WS_KH5 = WS_XH5 + 896ull*35*8;
static constexpr size_t WS_YH5 = WS_KH5 + 35ull*1792*8;
static constexpr size_t WS_S5P = WS_YH5 + 2048ull*35*8;
static constexpr size_t WS_TOTAL = WS_S5P + 2048ull*6*4;

// ---------------- constant-table offsets ----------------
struct ConstOffs {
  size_t A1, A2, A3, A4, A5;
  size_t S1, S2, S3, S4, S5;
  size_t WInt;
  size_t nF;
  size_t Fs2, Fso3;
  size_t Tw60, Tw34, Tw18, Tw10, Tw6;
  size_t Wn1, Wn2o, Wn3, Wn4, Wn5;
  size_t Wg1, Wg2, Wg3, Wg4;
  size_t nC;
};
static ConstOffs CO;
static float*  g_devF = nullptr;
static float2* g_devC = nullptr;

// ============================================================================
// Host: symmetric-tridiagonal eigensolver + Wigner-d builder
// ============================================================================
static void tqli(double* d, double* e, int n, double* z) {
  e[n-1] = 0.0;
  for (int l = 0; l < n; l++) {
    int iter = 0;
    int m;
    do {
      for (m = l; m < n-1; m++) {
        double dd = fabs(d[m]) + fabs(d[m+1]);
        if (fabs(e[m]) <= 1e-300 + 1e-14*dd) break;
      }
      if (m != l) {
        if (iter++ == 80) break;
        double g = (d[l+1]-d[l])/(2.0*e[l]);
        double r = hypot(g, 1.0);
        g = d[m]-d[l]+e[l]/(g + (g >= 0.0 ? fabs(r) : -fabs(r)));
        double s = 1.0, c = 1.0, p = 0.0;
        int i;
        r = 1.0;
        for (i = m-1; i >= l; i--) {
          double f = s*e[i], b = c*e[i];
          r = hypot(f, g);
          e[i+1] = r;
          if (r == 0.0) { d[i+1] -= p; e[m] = 0.0; break; }
          s = f/r; c = g/r;
          g = d[i+1]-p;
          r = (d[i]-g)*s + 2.0*c*b;
          p = s*r;
          d[i+1] = g+p;
          g = c*r-b;
          for (int k = 0; k < n; k++) {
            f = z[(size_t)k*n+i+1];
            z[(size_t)k*n+i+1] = s*z[(size_t)k*n+i] + c*f;
            z[(size_t)k*n+i]   = c*z[(size_t)k*n+i] - s*f;
          }
        }
        if (r == 0.0 && i >= l) continue;
        d[l] -= p; e[l] = g; e[m] = 0.0;
      }
    } while (m != l);
  }
}

struct Builder {
  std::vector<std::vector<double>> V, Lam;
  bool useExpm[30];

  Builder() {
    V.resize(30); Lam.resize(30);
    for (int l = 0; l < 30; l++) {
      int n = 2*l+1;
      std::vector<double> d(n, 0.0), e(n, 0.0), z((size_t)n*n, 0.0);
      for (int i = 0; i < n; i++) z[(size_t)i*n+i] = 1.0;
      for (int i = 0; i+1 < n; i++) {
        double m = (double)i - l;
        e[i] = -0.5*sqrt((double)l*(l+1) - m*(m+1.0));
      }
      if (n > 1) tqli(d.data(), e.data(), n, z.data());
      V[l] = std::move(z); Lam[l] = std::move(d);
    }
    std::vector<double> t((size_t)59*59);
    for (int l = 0; l < 30; l++) {
      useExpm[l] = false;
      if (l == 0) continue;
      int n = 2*l+1;
      eigD(l, 0.77, t.data());
      double corner = pow(cos(0.385), 2.0*l);
      double err = fabs(t[0] - corner) + fabs(t[(size_t)(n-1)*n + (n-1)] - corner);
      double s = 0.0;
      for (int c = 0; c < n; c++) s += t[c]*t[c];
      err += fabs(s - 1.0);
      if (!(err < 1e-8)) useExpm[l] = true;
    }
  }

  void eigD(int l, double beta, double* out) {
    int n = 2*l+1;
    const double* Vp = V[l].data();
    const double* lam = Lam[l].data();
    double ck[64], sk[64];
    for (int k = 0; k < n; k++) { ck[k] = cos(beta*lam[k]); sk[k] = sin(beta*lam[k]); }
    for (int a = 0; a < n; a++) {
      const double* va = Vp + (size_t)a*n;
      for (int c = 0; c < n; c++) {
        const double* vc = Vp + (size_t)c*n;
        int r = ((a - c) % 4 + 4) % 4;
        const double* f = (r & 1) ? sk : ck;
        double s = 0.0;
        for (int k = 0; k < n; k++) s += va[k]*vc[k]*f[k];
        out[(size_t)a*n + c] = (r >= 2) ? -s : s;
      }
    }
  }

  void expmD(int l, double beta, double* out) {
    int n = 2*l+1;
    int s = 0; double bl = fabs(beta)*(double)l + 1e-12;
    while (bl > 0.25) { bl *= 0.5; s++; }
    double sc = ldexp(beta, -s);
    std::vector<double> sup(n > 1 ? n-1 : 0);
    for (int i = 0; i+1 < n; i++) {
      double m = (double)i - l;
      sup[i] = 0.5*sqrt((double)l*(l+1) - m*(m+1.0))*sc;
    }
    std::vector<double> term((size_t)n*n, 0.0), acc((size_t)n*n, 0.0), t2((size_t)n*n);
    for (int i = 0; i < n; i++) { term[(size_t)i*n+i] = 1.0; acc[(size_t)i*n+i] = 1.0; }
    for (int k = 1; k <= 16; k++) {
      for (int r = 0; r < n; r++)
        for (int c = 0; c < n; c++) {
          double v = 0.0;
          if (c > 0)   v += term[(size_t)r*n + c-1]*sup[c-1];
          if (c+1 < n) v -= term[(size_t)r*n + c+1]*sup[c];
          t2[(size_t)r*n+c] = v/(double)k;
        }
      term.swap(t2);
      for (size_t i2 = 0; i2 < (size_t)n*n; i2++) acc[i2] += term[i2];
    }
    for (int t = 0; t < s; t++) {
      for (int r = 0; r < n; r++)
        for (int c = 0; c < n; c++) {
          double v = 0.0;
          for (int k = 0; k < n; k++) v += acc[(size_t)r*n+k]*acc[(size_t)k*n+c];
          t2[(size_t)r*n+c] = v;
        }
      acc.swap(t2);
    }
    std::memcpy(out, acc.data(), sizeof(double)*(size_t)n*n);
  }

  void buildD(int l, double beta, double* out) {
    if (useExpm[l]) expmD(l, beta, out); else eigD(l, beta, out);
  }
};

static std::vector<double> quadw_h(int b) {
  std::vector<double> w(2*b);
  for (int j = 0; j < 2*b; j++) {
    double s = 0;
    for (int k = 0; k < b; k++)
      s += sin(DPI*(2*j+1)*(2*k+1)/(4.0*b))/(double)(2*k+1);
    w[j] = (2.0/b)*sin(DPI*(2*j+1)/(4.0*b))*s;
  }
  return w;
}

static void build_all() {
  size_t o = 0;
  CO.A1 = o; o += 60ull*900;
  CO.A2 = o; o += 60ull*OQh(17);
  CO.A3 = o; o += 34ull*OQh(9);
  CO.A4 = o; o += 18ull*OQh(5);
  CO.A5 = o; o += 10ull*OQh(3);
  CO.S1 = o; o += 60ull*OQh(30);
  CO.S2 = o; o += 34ull*OQh(17);
  CO.S3 = o; o += 18ull*OQh(9);
  CO.S4 = o; o += 10ull*OQh(5);
  CO.S5 = o; o +=  6ull*OQh(3);
  CO.WInt = o; o += 8;
  CO.nF = o;
  size_t c = 0;
  CO.Fs2  = c; c += 6ull*900;
  CO.Fso3 = c; c += 36ull*OQh(17);
  CO.Tw60 = c; c += 60; CO.Tw34 = c; c += 34; CO.Tw18 = c; c += 18;
  CO.Tw10 = c; c += 10; CO.Tw6  = c; c += 6;
  CO.Wn1 = c; c += 30*60; CO.Wn2o = c; c += 17*34; CO.Wn3 = c; c += 9*18;
  CO.Wn4 = c; c += 5*10;  CO.Wn5 = c; c += 3*6;
  CO.Wg1 = c; c += 60*17; CO.Wg2 = c; c += 34*9; CO.Wg3 = c; c += 18*5;
  CO.Wg4 = c; c += 10*3;
  CO.nC = c;

  std::vector<float> HF(CO.nF, 0.f);
  std::vector<float> HC(2*CO.nC, 0.f);

  Builder B;
  auto betas = [](int b){ std::vector<double> v(2*b);
    for (int j = 0; j < 2*b; j++) v[j] = DPI*(2*j+1)/(4.0*b); return v; };
  auto w30 = quadw_h(30), w17 = quadw_h(17), w9 = quadw_h(9), w5 = quadw_h(5), w3 = quadw_h(3);
  std::vector<double> tmp((size_t)59*59);

  { auto bs = betas(30);
    for (int l = 0; l < 30; l++) { int n = 2*l+1;
      for (int j = 0; j < 60; j++) {
        B.buildD(l, bs[j], tmp.data());
        float* dst = HF.data() + CO.S1 + 60ull*OQh(l) + (size_t)j*n*n;
        for (int i2 = 0; i2 < n*n; i2++) dst[i2] = (float)((2*l+1)*tmp[i2]);
        if (l < 17) {
          float* dA = HF.data() + CO.A2 + 60ull*OQh(l) + (size_t)j*n*n;
          for (int i2 = 0; i2 < n*n; i2++) dA[i2] = (float)(tmp[i2]*w30[j]);
        }
        float* dA1 = HF.data() + CO.A1 + 60ull*l*l + (size_t)j*n;
        for (int mi = 0; mi < n; mi++) dA1[mi] = (float)(tmp[(size_t)mi*n + l]*w30[j]);
      } } }
  { auto bs = betas(17);
    for (int l = 0; l < 17; l++) { int n = 2*l+1;
      for (int j = 0; j < 34; j++) {
        B.buildD(l, bs[j], tmp.data());
        float* dst = HF.data() + CO.S2 + 34ull*OQh(l) + (size_t)j*n*n;
        for (int i2 = 0; i2 < n*n; i2++) dst[i2] = (float)((2*l+1)*tmp[i2]);
        if (l < 9) {
          float* dA = HF.data() + CO.A3 + 34ull*OQh(l) + (size_t)j*n*n;
          for (int i2 = 0; i2 < n*n; i2++) dA[i2] = (float)(tmp[i2]*w17[j]);
        } } } }
  { auto bs = betas(9);
    for (int l = 0; l < 9; l++) { int n = 2*l+1;
      for (int j = 0; j < 18; j++) {
        B.buildD(l, bs[j], tmp.data());
        float* dst = HF.data() + CO.S3 + 18ull*OQh(l) + (size_t)j*n*n;
        for (int i2 = 0; i2 < n*n; i2++) dst[i2] = (float)((2*l+1)*tmp[i2]);
        if (l < 5) {
          float* dA = HF.data() + CO.A4 + 18ull*OQh(l) + (size_t)j*n*n;
          for (int i2 = 0; i2 < n*n; i2++) dA[i2] = (float)(tmp[i2]*w9[j]);
        } } } }
  { auto bs = betas(5);
    for (int l = 0; l < 5; l++) { int n = 2*l+1;
      for (int j = 0; j < 10; j++) {
        B.buildD(l, bs[j], tmp.data());
        float* dst = HF.data() + CO.S4 + 10ull*OQh(l) + (size_t)j*n*n;
        for (int i2 = 0; i2 < n*n; i2++) dst[i2] = (float)((2*l+1)*tmp[i2]);
        if (l < 3) {
          float* dA = HF.data() + CO.A5 + 10ull*OQh(l) + (size_t)j*n*n;
          for (int i2 = 0; i2 < n*n; i2++) dA[i2] = (float)(tmp[i2]*w5[j]);
        } } } }
  { auto bs = betas(3);
    for (int l = 0; l < 3; l++) { int n = 2*l+1;
      for (int j = 0; j < 6; j++) {
        B.buildD(l, bs[j], tmp.data());
        float* dst = HF.data() + CO.S5 + 6ull*OQh(l) + (size_t)j*n*n;
        for (int i2 = 0; i2 < n*n; i2++) dst[i2] = (float)((2*l+1)*tmp[i2]);
      } } }
  { double beta = DPI/16.0;
    for (int l = 0; l < 30; l++) { int n = 2*l+1;
      B.buildD(l, beta, tmp.data());
      for (int p = 0; p < 6; p++) {
        double al = 2.0*DPI*p/6.0;
        for (int mi = 0; mi < n; mi++) {
          double ph = al*(double)(mi - l);
          double dr = tmp[(size_t)mi*n + l];
          size_t off = CO.Fs2 + 6ull*l*l + (size_t)p*n + mi;
          HC[2*off]   = (float)(dr*cos(ph));
          HC[2*off+1] = (float)(dr*sin(ph));
        } }
      if (l < 17) {
        for (int p = 0; p < 36; p++) {
          double al = 2.0*DPI*(p/6)/6.0, ga = 2.0*DPI*(p%6)/6.0;
          for (int mi = 0; mi < n; mi++)
            for (int ni = 0; ni < n; ni++) {
              double ph = al*(double)(mi - l) + ga*(double)(ni - l);
              double dr = tmp[(size_t)mi*n + ni];
              size_t off = CO.Fso3 + 36ull*OQh(l) + (size_t)p*n*n + (size_t)mi*n + ni;
              HC[2*off]   = (float)(dr*cos(ph));
              HC[2*off+1] = (float)(dr*sin(ph));
            } } } } }
  auto fillTw = [&](size_t ofs, int N){
    for (int t = 0; t < N; t++) {
      HC[2*(ofs+t)]   = (float)cos(2.0*DPI*t/N);
      HC[2*(ofs+t)+1] = (float)sin(2.0*DPI*t/N);
    } };
  fillTw(CO.Tw60, 60); fillTw(CO.Tw34, 34); fillTw(CO.Tw18, 18);
  fillTw(CO.Tw10, 10); fillTw(CO.Tw6, 6);
  auto fillWn = [&](size_t ofs, int BQ, int N){
    for (int n = 0; n < BQ; n++)
      for (int cc2 = 0; cc2 < N; cc2++) {
        double f = (n == 0) ? 1.0 : 2.0;
        HC[2*(ofs + (size_t)n*N + cc2)]   = (float)(f*cos(2.0*DPI*n*cc2/N));
        HC[2*(ofs + (size_t)n*N + cc2)+1] = (float)(f*sin(2.0*DPI*n*cc2/N));
      } };
  auto fillWg = [&](size_t ofs, int N, int KT){
    for (int cc2 = 0; cc2 < N; cc2++)
      for (int k = 0; k < KT; k++) {
        HC[2*(ofs + (size_t)cc2*KT + k)]   = (float)cos(2.0*DPI*k*cc2/N);
        HC[2*(ofs + (size_t)cc2*KT + k)+1] = (float)(-sin(2.0*DPI*k*cc2/N));
      } };
  fillWn(CO.Wn1, 30, 60); fillWn(CO.Wn2o, 17, 34); fillWn(CO.Wn3, 9, 18);
  fillWn(CO.Wn4, 5, 10);  fillWn(CO.Wn5, 3, 6);
  fillWg(CO.Wg1, 60, 17); fillWg(CO.Wg2, 34, 9); fillWg(CO.Wg3, 18, 5);
  fillWg(CO.Wg4, 10, 3);
  for (int j = 0; j < 6; j++) HF[CO.WInt + j] = (float)(w3[j]/36.0);

  size_t fb = CO.nF * sizeof(float);
  size_t fbA = (fb + 255) & ~(size_t)255;
  size_t cb = CO.nC * sizeof(float2);
  void* base = nullptr;
  if (hipMalloc(&base, fbA + cb) != hipSuccess || !base) return;
  if (hipMemcpy(base, HF.data(), fb, hipMemcpyHostToDevice) != hipSuccess) return;
  if (hipMemcpy((char*)base + fbA, HC.data(), cb, hipMemcpyHostToDevice) != hipSuccess) return;
  (void)hipDeviceSynchronize();
  g_devF = (float*)base;
  g_devC = (float2*)((char*)base + fbA);
}
namespace { struct InitOnce { InitOnce(){ build_all(); } } g_once; }

// ============================================================================
// Device helpers
// ============================================================================
__device__ __forceinline__ int OQ(int l) { return l*(4*l*l - 1)/3; }
__device__ __forceinline__ int lFromQ(int q, int L) {
  int l = 0;
  while (l+1 < L && OQ(l+1) <= q) l++;
  return l;
}
__device__ __forceinline__ int lsq(int q) {
  int l = (int)sqrtf((float)q);
  while ((l+1)*(l+1) <= q) l++;
  while (l*l > q) l--;
  return l;
}
__device__ __forceinline__ void rotf(float2& r, float2 s) {
  float t = r.x*s.x - r.y*s.y;
  r.y = r.x*s.y + r.y*s.x;
  r.x = t;
}

// ---------------- kernel FT: s2 ----------------
__global__ __launch_bounds__(256) void k_kh_s2(
    const float* __restrict__ ks2, const float2* __restrict__ F, float2* __restrict__ kh)
{
  int id = blockIdx.x*blockDim.x + threadIdx.x;
  if (id >= 1800) return;
  int q = id >> 1, o = id & 1;
  int l = lsq(q); int W = 2*l+1; int mi = q - l*l;
  const float2* Fb = F + 6ull*l*l;
  float ax = 0.f, ay = 0.f;
  for (int p = 0; p < 6; p++) {
    float kv = ks2[o*6 + p];
    float2 f = Fb[p*W + mi];
    ax += kv*f.x; ay += kv*f.y;
  }
  kh[(size_t)q*2 + o] = make_float2(ax, ay);
}

// ---------------- kernel FT: so3 ----------------
__global__ __launch_bounds__(256) void k_kh_so3(
    const float* __restrict__ kk, const float2* __restrict__ F,
    float2* __restrict__ kh, int L, int fi, int fo)
{
  int id = blockIdx.x*blockDim.x + threadIdx.x;
  int ff = fi*fo;
  if (id >= OQ(L)*ff) return;
  int q = id / ff, r = id - q*ff;
  int i = r / fo, o = r - i*fo;
  int l = lFromQ(q, L); int W = 2*l+1; int W21 = W*W;
  int rem = q - OQ(l);
  const float2* Fb = F + 36ull*OQ(l) + rem;
  const float* kb = kk + (size_t)(i*fo + o)*36;
  float ax = 0.f, ay = 0.f;
  for (int p = 0; p < 36; p++) {
    float kv = kb[p];
    float2 f = Fb[(size_t)p*W21];
    ax += kv*f.x; ay += kv*f.y;
  }
  kh[(size_t)q*ff + r] = make_float2(ax, ay);
}

// ---------------- stage-1 analysis: alpha DFT ----------------
__global__ __launch_bounds__(64) void k_s1_fftA(
    const float* __restrict__ x, const float2* __restrict__ tw, float2* __restrict__ XF1)
{
  __shared__ float row[60];
  int b = blockIdx.x / 60, j = blockIdx.x - b*60;
  int t = threadIdx.x;
  if (t < 60) row[t] = x[((size_t)b*60 + j)*60 + t];
  __syncthreads();
  if (t < 30) {
    float ax = 0.f, ay = 0.f;
    int ti = 0;
    for (int a = 0; a < 60; a++) {
      float2 w = tw[ti];
      ax += row[a]*w.x; ay -= row[a]*w.y;
      ti += t; if (ti >= 60) ti -= 60;
    }
    XF1[((size_t)b*60 + j)*30 + t] = make_float2(ax, ay);
  }
}

// ---------------- stage-1 beta contraction ----------------
__global__ __launch_bounds__(256) void k_s1_coef(
    const float2* __restrict__ XF1, const float* __restrict__ dA1, float2* __restrict__ xh1)
{
  int id = blockIdx.x*blockDim.x + threadIdx.x;
  if (id >= 32*900) return;
  int b = id / 900, q = id - b*900;
  int l = lsq(q); int W = 2*l+1; int mi = q - l*l; int m = mi - l;
  const float* dp = dA1 + 60ull*l*l + mi;
  const float2* xb = XF1 + (size_t)b*60*30;
  int ma = m >= 0 ? m : -m;
  float sg = m >= 0 ? 1.f : -1.f;
  float ax = 0.f, ay = 0.f;
  for (int j = 0; j < 60; j++) {
    float2 xf = xb[j*30 + ma];
    float d = dp[(size_t)j*W];
    ax += d*xf.x; ay += sg*d*xf.y;
  }
  xh1[id] = make_float2(ax, ay);
}

// ---------------- stage-1 spectral product ----------------
__global__ __launch_bounds__(256) void k_s1_yh(
    const float2* __restrict__ xh1, const float2* __restrict__ kh1, float2* __restrict__ yh1)
{
  int id = blockIdx.x*blockDim.x + threadIdx.x;
  if (id >= 64*35990) return;
  int bo = id / 35990, q = id - bo*35990;
  int b = bo >> 1, o = bo & 1;
  int l = lFromQ(q, 30); int W = 2*l+1;
  int rem = q - OQ(l); int mi = rem / W, ni = rem - mi*W;
  float2 xv = xh1[(size_t)b*900 + l*l + mi];
  float2 kv = kh1[(size_t)(l*l + ni)*2 + o];
  yh1[id] = make_float2(xv.x*kv.x + xv.y*kv.y, xv.y*kv.x - xv.x*kv.y);
}

// ---------------- generic spectral product ----------------
__global__ __launch_bounds__(256) void k_yh(
    const float2* __restrict__ xh, const float2* __restrict__ kh,
    float2* __restrict__ yh, int L, int fi, int fo, int Qtot)
{
  int id = blockIdx.x*blockDim.x + threadIdx.x;
  if (id >= 32*fo*Qtot) return;
  int bo = id / Qtot, q = id - bo*Qtot;
  int b = bo / fo, o = bo - b*fo;
  int l = lFromQ(q, L); int W = 2*l+1;
  int rem = q - OQ(l); int mi = rem / W, ni = rem - mi*W;
  int ff = fi*fo;
  const float2* xb = xh + ((size_t)b*fi)*Qtot + OQ(l) + mi*W;
  const float2* kb = kh + ((size_t)(OQ(l) + ni*W))*ff + o;
  float ax = 0.f, ay = 0.f;
  for (int i = 0; i < fi; i++) {
    const float2* xrow = xb + (size_t)i*Qtot;
    const float2* krow = kb + (size_t)i*fo;
    for (int k = 0; k < W; k++) {
      float2 xv = xrow[k];
      float2 kv = krow[(size_t)k*ff];
      ax += xv.x*kv.x + xv.y*kv.y;
      ay += xv.y*kv.x - xv.x*kv.y;
    }
  }
  yh[id] = make_float2(ax, ay);
}

// ---------------- generic beta contraction ----------------
__global__ __launch_bounds__(256) void k_coef(
    const float2* __restrict__ xt, const float* __restrict__ dA,
    float2* __restrict__ xh, int L, int nj, int KT, int MT, int Qtot, int nbi)
{
  int id = blockIdx.x*blockDim.x + threadIdx.x;
  if (id >= nbi*Qtot) return;
  int bi = id / Qtot, q = id - bi*Qtot;
  int l = lFromQ(q, L); int W = 2*l+1; int W21 = W*W;
  int rem = q - OQ(l); int mi = rem / W, ki = rem - mi*W;
  int m = mi - l, ks = ki - l;
  const float* dAp = dA + (size_t)nj*OQ(l) + rem;
  int MTKT = MT*KT;
  int pidx; float sgn;
  if (ks >= 0) { pidx = (m + (KT-1))*KT + ks;  sgn =  1.f; }
  else         { pidx = (-m + (KT-1))*KT - ks; sgn = -1.f; }
  const float2* xb = xt + (size_t)bi*nj*MTKT + pidx;
  float ax = 0.f, ay = 0.f;
  for (int j = 0; j < nj; j++) {
    float2 xv = xb[(size_t)j*MTKT];
    float d = dAp[(size_t)j*W21];
    ax += d*xv.x; ay += sgn*d*xv.y;
  }
  xh[id] = make_float2(ax, ay);
}

// ============================================================================
// Fused synthesis v3 (stages 1-3): Hermitian half-plane + radix-2 DFT phases
// + register rotator recurrences. LDS ping-pong A -> B -> A -> B:
//   A: P[W2][CP]            then SS/SD[N][NH]
//   B: Tm[N][CP]            then USS/USD[NH][KTP]
// ============================================================================
template<int BQ, int N, int KT, int MT, int TPB>
__global__ __launch_bounds__(TPB) void k_synth3(
    const float2* __restrict__ yh, const float* __restrict__ dS,
    const float2* __restrict__ twN, float2* __restrict__ xt)
{
  constexpr int W2  = 2*BQ - 1;
  constexpr int NH  = N/2;
  constexpr int CP  = (BQ+3) & ~3;          // padded cols (zeroed)
  constexpr int KTP = (KT+1) & ~1;
  constexpr int QT  = BQ*(4*BQ*BQ - 1)/3;
  constexpr int R3  = (N%4 == 0) ? 4 : 2;   // rows/thread in phase 3
  constexpr int RP  = (NH%2 == 0) ? 2 : 1;  // (a,a+NH) pairs/thread in phase 4
  constexpr int SZA0 = (W2*CP*8 > 2*N*NH*4) ? W2*CP*8 : 2*N*NH*4;
  constexpr int SZA  = (SZA0 + 15) & ~15;
  constexpr int SZB0 = (N*CP*8 > 2*NH*KTP*8) ? N*CP*8 : 2*NH*KTP*8;
  constexpr int SZB  = (SZB0 + 15) & ~15;
  __shared__ __align__(16) char smem[SZA + SZB + N*8];
  float2* P   = (float2*)smem;              // [W2][CP]
  float*  SS  = (float*)smem;               // [N][NH]  (overlay after P dead)
  float*  SD  = SS + N*NH;
  float2* Tm  = (float2*)(smem + SZA);      // [N][CP]
  float2* USS = (float2*)(smem + SZA);      // [NH][KTP] (overlay after Tm dead)
  float2* USD = USS + NH*KTP;
  float2* twl = (float2*)(smem + SZA + SZB);

  const int tid = threadIdx.x;
  int nwg = gridDim.x, bidx = blockIdx.x;
  int per = nwg >> 3;
  int swz = (bidx & 7)*per + (bidx >> 3);   // bijective: grids %8==0
  int bo = swz / N, j = swz - bo*N;

  for (int t = tid; t < N; t += TPB) twl[t] = twN[t];

  // --- phase 1: Wigner scatter, n>=0 half (cols >= BQ zero-padded)
  const float2* yhb = yh + (size_t)bo*QT;
  for (int idx = tid; idx < W2*CP; idx += TPB) {
    int pm = idx / CP, n = idx - pm*CP;
    float ax = 0.f, ay = 0.f;
    if (n < BQ) {
      int m = pm - (BQ-1);
      int am = m < 0 ? -m : m;
      int lmin = am > n ? am : n;
      int base = lmin*(4*lmin*lmin - 1)/3;
      for (int l = lmin; l < BQ; l++) {
        int Wl = 2*l+1;
        float2 y = yhb[base + (m+l)*Wl + (n+l)];
        float d = dS[(size_t)N*base + (size_t)j*Wl*Wl + (m+l)*Wl + (n+l)];
        ax += d*y.x; ay += d*y.y;
        base += Wl*Wl;
      }
    }
    P[idx] = make_float2(ax, ay);
  }
  __syncthreads();

  // --- phase 2: m-iDFT (alpha), radix-2 over pm parity, rotator recurrence.
  // T[a] = ph_a (E + w^a O); T[a+NH] = sgn * ph_a (E - w^a O)
  {
    constexpr int CG = CP/4;
    constexpr float SGN = ((BQ-1) & 1) ? -1.f : 1.f;
    const float4* P4 = (const float4*)P;
    for (int it = tid; it < NH*CG; it += TPB) {
      int a = it / CG, cg = it - a*CG;
      float2 s2 = twl[2*a];
      float2 r = make_float2(1.f, 0.f);
      float4 E0 = {0,0,0,0}, E1 = {0,0,0,0}, O0 = {0,0,0,0}, O1 = {0,0,0,0};
      for (int jj = 0; jj < BQ-1; jj++) {
        float4 e0 = P4[(2*jj)*(CP/2) + 2*cg];
        float4 e1 = P4[(2*jj)*(CP/2) + 2*cg + 1];
        float4 o0 = P4[(2*jj+1)*(CP/2) + 2*cg];
        float4 o1 = P4[(2*jj+1)*(CP/2) + 2*cg + 1];
        E0.x += e0.x*r.x - e0.y*r.y; E0.y += e0.x*r.y + e0.y*r.x;
        E0.z += e0.z*r.x - e0.w*r.y; E0.w += e0.z*r.y + e0.w*r.x;
        E1.x += e1.x*r.x - e1.y*r.y; E1.y += e1.x*r.y + e1.y*r.x;
        E1.z += e1.z*r.x - e1.w*r.y; E1.w += e1.z*r.y + e1.w*r.x;
        O0.x += o0.x*r.x - o0.y*r.y; O0.y += o0.x*r.y + o0.y*r.x;
        O0.z += o0.z*r.x - o0.w*r.y; O0.w += o0.z*r.y + o0.w*r.x;
        O1.x += o1.x*r.x - o1.y*r.y; O1.y += o1.x*r.y + o1.y*r.x;
        O1.z += o1.z*r.x - o1.w*r.y; O1.w += o1.z*r.y + o1.w*r.x;
        rotf(r, s2);
      }
      { // final even term pm = 2(BQ-1)
        float4 e0 = P4[(2*(BQ-1))*(CP/2) + 2*cg];
        float4 e1 = P4[(2*(BQ-1))*(CP/2) + 2*cg + 1];
        E0.x += e0.x*r.x - e0.y*r.y; E0.y += e0.x*r.y + e0.y*r.x;
        E0.z += e0.z*r.x - e0.w*r.y; E0.w += e0.z*r.y + e0.w*r.x;
        E1.x += e1.x*r.x - e1.y*r.y; E1.y += e1.x*r.y + e1.y*r.x;
        E1.z += e1.z*r.x - e1.w*r.y; E1.w += e1.z*r.y + e1.w*r.x;
      }
      float2 wa = twl[a];
      int pidx = (N - (a*(BQ-1)) % N) % N;
      float2 ph = twl[pidx];
      int c0 = 4*cg;
      auto doCol = [&](float ex, float ey, float ox, float oy, int col) {
        float gx = ox*wa.x - oy*wa.y, gy = ox*wa.y + oy*wa.x;
        float px = ex + gx, py = ey + gy;
        float qx = ex - gx, qy = ey - gy;
        Tm[a*CP + col]        = make_float2(px*ph.x - py*ph.y, px*ph.y + py*ph.x);
        Tm[(a+NH)*CP + col]   = make_float2(SGN*(qx*ph.x - qy*ph.y), SGN*(qx*ph.y + qy*ph.x));
      };
      doCol(E0.x, E0.y, O0.x, O0.y, c0+0);
      doCol(E0.z, E0.w, O0.z, O0.w, c0+1);
      doCol(E1.x, E1.y, O1.x, O1.y, c0+2);
      doCol(E1.z, E1.w, O1.z, O1.w, c0+3);
    }
  }
  __syncthreads();

  // --- phase 3: real n-iDFT (gamma) via Hermitian fold, radix-2 over c,
  //     ReLU, and fused Ssum/Sdif (k-parity pre-combine for phase 4).
  // S[a][c] = 2(E'+O') - T0.x ; S[a][c+NH] = 2(E'-O') - T0.x
  {
    constexpr int NO3 = BQ/2;            // odd-n count
    constexpr int NRG = N/R3;
    for (int it = tid; it < NRG*NH; it += TPB) {
      int rg = it / NH, c = it - rg*NH;
      int a0 = rg*R3;
      float2 se = twl[2*c];
      float2 re = make_float2(1.f, 0.f);
      float2 ro = twl[c];
      float er[R3], orr[R3];
      #pragma unroll
      for (int rr = 0; rr < R3; rr++) { er[rr] = 0.f; orr[rr] = 0.f; }
      for (int jj = 0; jj < NO3; jj++) {
        #pragma unroll
        for (int rr = 0; rr < R3; rr++) {
          float4 tv = *(const float4*)&Tm[(a0+rr)*CP + 2*jj];
          er[rr]  += tv.x*re.x - tv.y*re.y;
          orr[rr] += tv.z*ro.x - tv.w*ro.y;
        }
        rotf(re, se); rotf(ro, se);
      }
      if constexpr ((BQ & 1) != 0) {     // BQ odd: last even n = BQ-1
        #pragma unroll
        for (int rr = 0; rr < R3; rr++) {
          float2 tv = Tm[(a0+rr)*CP + (BQ-1)];
          er[rr] += tv.x*re.x - tv.y*re.y;
        }
      }
      #pragma unroll
      for (int rr = 0; rr < R3; rr++) {
        float t0x = Tm[(a0+rr)*CP].x;
        float s0 = fmaxf(2.f*(er[rr] + orr[rr]) - t0x, 0.f);
        float s1 = fmaxf(2.f*(er[rr] - orr[rr]) - t0x, 0.f);
        SS[(a0+rr)*NH + c] = s0 + s1;
        SD[(a0+rr)*NH + c] = s0 - s1;
      }
    }
  }
  __syncthreads();

  // --- phase 4: gamma fwd DFT, radix-2 over k parity, fused Usum/Udif
  //     (m-parity pre-combine for phase 5). Thread owns RP pairs (a, a+NH).
  {
    for (int it = tid; it < (NH/RP)*KT; it += TPB) {
      int g = it / KT, k = it - g*KT;
      int a0 = g*RP;
      const float* Sp = (k & 1) ? SD : SS;
      float2 st = twl[k]; st.y = -st.y;     // cis(-2pi k/N)
      float2 r = make_float2(1.f, 0.f);
      float ux[2*RP], uy[2*RP];
      #pragma unroll
      for (int q2 = 0; q2 < 2*RP; q2++) { ux[q2] = 0.f; uy[q2] = 0.f; }
      for (int c = 0; c < NH; c++) {
        #pragma unroll
        for (int pp = 0; pp < RP; pp++) {
          float sl = Sp[(a0+pp)*NH + c];
          float sh = Sp[(a0+pp+NH)*NH + c];
          ux[2*pp]   += sl*r.x; uy[2*pp]   += sl*r.y;
          ux[2*pp+1] += sh*r.x; uy[2*pp+1] += sh*r.y;
        }
        rotf(r, st);
      }
      #pragma unroll
      for (int pp = 0; pp < RP; pp++) {
        USS[(a0+pp)*KTP + k] = make_float2(ux[2*pp] + ux[2*pp+1], uy[2*pp] + uy[2*pp+1]);
        USD[(a0+pp)*KTP + k] = make_float2(ux[2*pp] - ux[2*pp+1], uy[2*pp] - uy[2*pp+1]);
      }
    }
  }
  __syncthreads();

  // --- phase 5: alpha fwd DFT, radix-2 over m parity (Up = m even ? USS : USD)
  {
    float2* xtb = xt + ((size_t)bo*N + j)*(MT*KT);
    constexpr int KG = KTP/2;
    for (int it = tid; it < MT*KG; it += TPB) {
      int pm2 = it / KG, kg = it - pm2*KG;
      int m = pm2 - (KT-1);
      int mm = m < 0 ? m + N : m;
      const float2* Up = (m & 1) ? USD : USS;
      float2 st = twl[mm];
      float2 r = make_float2(1.f, 0.f);
      float a0x = 0.f, a0y = 0.f, a1x = 0.f, a1y = 0.f;
      for (int a = 0; a < NH; a++) {
        float4 u = *(const float4*)&Up[a*KTP + 2*kg];
        a0x += u.x*r.x + u.y*r.y;  a0y += u.y*r.x - u.x*r.y;   // u * conj(r)
        a1x += u.z*r.x + u.w*r.y;  a1y += u.w*r.x - u.z*r.y;
        rotf(r, st);
      }
      int k0 = 2*kg;
      xtb[pm2*KT + k0] = make_float2(a0x, a0y);
      if (k0 + 1 < KT) xtb[pm2*KT + k0 + 1] = make_float2(a1x, a1y);
    }
  }
}

// ============================================================================
// Fused synthesis v2 (kept for stage 4 and the INTEG stage — tiny FLOP)
// ============================================================================
template<int BQ, int N, int KT, int MT, int INTEG, int NPAIR, int TPB>
__global__ __launch_bounds__(TPB) void k_synth2(
    const float2* __restrict__ yh, const float* __restrict__ dS,
    const float2* __restrict__ twN, const float2* __restrict__ Wn2,
    const float2* __restrict__ Wg, float2* __restrict__ xt,
    float* __restrict__ s5p, const float* __restrict__ wInt)
{
  constexpr int W2 = 2*BQ - 1;
  constexpr int QT = BQ*(4*BQ*BQ - 1)/3;
  constexpr int SZA = (((W2*BQ*8 > N*N*4) ? W2*BQ*8 : N*N*4) + 15) & ~15;
  constexpr int SZB0 = (N*BQ*8 > N*KT*8) ? N*BQ*8 : N*KT*8;
  constexpr int SZB1 = (SZB0 > TPB*4) ? SZB0 : TPB*4;
  constexpr int SZB = (SZB1 + 15) & ~15;
  __shared__ __align__(16) char smem[SZA + SZB + N*8];
  float2* P   = (float2*)smem;
  float*  S   = (float*)smem;
  float2* Tm  = (float2*)(smem + SZA);
  float2* U   = (float2*)(smem + SZA);
  float*  red = (float*)(smem + SZA);
  float2* twl = (float2*)(smem + SZA + SZB);

  const int tid = threadIdx.x;
  int bidx = blockIdx.x, nwg = gridDim.x;
  int per = nwg >> 3;
  int swz = (bidx & 7)*per + (bidx >> 3);
  int bo = swz / N, j = swz - bo*N;

  for (int t = tid; t < N; t += TPB) twl[t] = twN[t];
  __syncthreads();

  const float2* yhb = yh + (size_t)bo*QT;
  for (int idx = tid; idx < W2*BQ; idx += TPB) {
    int pm = idx / BQ, n = idx - pm*BQ;
    int m = pm - (BQ-1);
    int am = m < 0 ? -m : m;
    int lmin = am > n ? am : n;
    int base = lmin*(4*lmin*lmin - 1)/3;
    float ax = 0.f, ay = 0.f;
    for (int l = lmin; l < BQ; l++) {
      int Wl = 2*l+1;
      float2 y = yhb[base + (m+l)*Wl + (n+l)];
      float d = dS[(size_t)N*base + (size_t)j*Wl*Wl + (m+l)*Wl + (n+l)];
      ax += d*y.x; ay += d*y.y;
      base += Wl*Wl;
    }
    P[idx] = make_float2(ax, ay);
  }
  __syncthreads();

  for (int idx = tid; idx < (N/2)*BQ; idx += TPB) {
    int ag = idx / BQ, n = idx - ag*BQ;
    int a0 = 2*ag, a1 = a0 + 1;
    int t0 = (N - (a0*(BQ-1)) % N) % N;
    int t1 = (N - (a1*(BQ-1)) % N) % N;
    float2 A0 = {0,0}, A1 = {0,0};
    for (int pm = 0; pm < W2; pm++) {
      float2 p = P[pm*BQ + n];
      float2 w0 = twl[t0], w1 = twl[t1];
      A0.x += p.x*w0.x - p.y*w0.y; A0.y += p.x*w0.y + p.y*w0.x;
      A1.x += p.x*w1.x - p.y*w1.y; A1.y += p.x*w1.y + p.y*w1.x;
      t0 += a0; if (t0 >= N) t0 -= N;
      t1 += a1; if (t1 >= N) t1 -= N;
    }
    Tm[a0*BQ + n] = A0;
    Tm[a1*BQ + n] = A1;
  }
  __syncthreads();

  {
    constexpr int CG = N/2;
    const float4* WnR = (const float4*)Wn2;
    for (int idx = tid; idx < N*CG; idx += TPB) {
      int a = idx / CG, cg = idx - a*CG;
      float s0 = 0.f, s1 = 0.f;
      const float2* TmA = Tm + a*BQ;
      for (int n = 0; n < BQ; n++) {
        float2 T = TmA[n];
        float4 w = WnR[n*CG + cg];
        s0 += T.x*w.x - T.y*w.y;
        s1 += T.x*w.z - T.y*w.w;
      }
      s0 = fmaxf(s0, 0.f); s1 = fmaxf(s1, 0.f);
      *(float2*)&S[a*N + 2*cg] = make_float2(s0, s1);
    }
  }
  __syncthreads();

  if constexpr (!INTEG) {
    for (int idx = tid; idx < (N/2)*KT; idx += TPB) {
      int ag = idx / KT, k = idx - ag*KT;
      int a0 = 2*ag, a1 = a0 + 1;
      float u0x=0.f,u0y=0.f,u1x=0.f,u1y=0.f;
      const float* S0 = S + a0*N;
      const float* S1 = S + a1*N;
      for (int c = 0; c < N; c++) {
        float2 w = Wg[c*KT + k];
        u0x += S0[c]*w.x; u0y += S0[c]*w.y;
        u1x += S1[c]*w.x; u1y += S1[c]*w.y;
      }
      U[a0*KT + k] = make_float2(u0x, u0y);
      U[a1*KT + k] = make_float2(u1x, u1y);
    }
    __syncthreads();

    float2* xtb = xt + ((size_t)bo*N + j)*(MT*KT);
    for (int idx = tid; idx < MT*KT; idx += TPB) {
      int pm2 = idx / KT, k = idx - pm2*KT;
      int m = pm2 - (KT-1);
      float ax = 0.f, ay = 0.f;
      int t = 0;
      for (int a = 0; a < N; a++) {
        float2 u = U[a*KT + k];
        float2 w = twl[t];
        ax += u.x*w.x + u.y*w.y;
        ay += u.y*w.x - u.x*w.y;
        t += m; if (t < 0) t += N; else if (t >= N) t -= N;
      }
      xtb[idx] = make_float2(ax, ay);
    }
  } else {
    float part = 0.f;
    for (int idx = tid; idx < N*N; idx += TPB) part += S[idx];
    red[tid] = part;
    __syncthreads();
    for (int off2 = TPB >> 1; off2 > 0; off2 >>= 1) {
      if (tid < off2) red[tid] += red[tid + off2];
      __syncthreads();
    }
    if (tid == 0) s5p[bo*N + j] = red[0]*wInt[j];
  }
}

// ---------------- head: integrate-reduce + 3x (batchnorm, linear) ----------
__global__ __launch_bounds__(256) void k_mlp(
    const float* __restrict__ s5p,
    const float* __restrict__ g1, const float* __restrict__ be1,
    const float* __restrict__ w1, const float* __restrict__ b1,
    const float* __restrict__ g2, const float* __restrict__ be2,
    const float* __restrict__ w2, const float* __restrict__ b2,
    const float* __restrict__ g3, const float* __restrict__ be3,
    const float* __restrict__ w3, const float* __restrict__ b3,
    float* __restrict__ out)
{
  __shared__ float A[2048], Bs[2048], C[1024], mu[64], iv[64];
  int tid = threadIdx.x;
  for (int idx = tid; idx < 2048; idx += 256) {
    float s = 0.f;
    #pragma unroll
    for (int j = 0; j < 6; j++) s += s5p[idx*6 + j];
    A[idx] = s;
  }
  __syncthreads();
  if (tid < 64) {
    float m = 0.f; for (int b = 0; b < 32; b++) m += A[b*64 + tid]; m *= (1.f/32);
    float v = 0.f; for (int b = 0; b < 32; b++) { float d = A[b*64+tid]-m; v += d*d; } v *= (1.f/32);
    mu[tid] = m; iv[tid] = rsqrtf(v + 1e-5f)*g1[tid];
  }
  __syncthreads();
  for (int idx = tid; idx < 2048; idx += 256) {
    int f = idx & 63;
    A[idx] = (A[idx]-mu[f])*iv[f] + be1[f];
  }
  __syncthreads();
  for (int idx = tid; idx < 2048; idx += 256) {
    int b = idx >> 6, fo = idx & 63;
    float s = b1[fo];
    for (int f = 0; f < 64; f++) s += A[b*64+f]*w1[f*64+fo];
    Bs[idx] = fmaxf(s, 0.f);
  }
  __syncthreads();
  if (tid < 64) {
    float m = 0.f; for (int b = 0; b < 32; b++) m += Bs[b*64+tid]; m *= (1.f/32);
    float v = 0.f; for (int b = 0; b < 32; b++) { float d = Bs[b*64+tid]-m; v += d*d; } v *= (1.f/32);
    mu[tid] = m; iv[tid] = rsqrtf(v + 1e-5f)*g2[tid];
  }
  __syncthreads();
  for (int idx = tid; idx < 2048; idx += 256) {
    int f = idx & 63;
    Bs[idx] = (Bs[idx]-mu[f])*iv[f] + be2[f];
  }
  __syncthreads();
  for (int idx = tid; idx < 1024; idx += 256) {
    int b = idx >> 5, fo = idx & 31;
    float s = b2[fo];
    for (int f = 0; f < 64; f++) s += Bs[b*64+f]*w2[f*32+fo];
    C[idx] = fmaxf(s, 0.f);
  }
  __syncthreads();
  if (tid < 32) {
    float m = 0.f; for (int b = 0; b < 32; b++) m += C[b*32+tid]; m *= (1.f/32);
    float v = 0.f; for (int b = 0; b < 32; b++) { float d = C[b*32+tid]-m; v += d*d; } v *= (1.f/32);
    mu[tid] = m; iv[tid] = rsqrtf(v + 1e-5f)*g3[tid];
  }
  __syncthreads();
  for (int idx = tid; idx < 1024; idx += 256) {
    int f = idx & 31;
    C[idx] = (C[idx]-mu[f])*iv[f] + be3[f];
  }
  __syncthreads();
  for (int idx = tid; idx < 320; idx += 256) {
    int b = idx/10, cc = idx - b*10;
    float s = b3[cc];
    for (int f = 0; f < 32; f++) s += C[b*32+f]*w3[f*10+cc];
    out[idx] = s;
  }
}

// ============================================================================
// launch
// ============================================================================
static inline int cdiv_h(int a, int b) { return (a + b - 1)/b; }

extern "C" void kernel_launch(void* const* d_in, const int* in_sizes, int n_in,
                              void* d_out, int out_size, void* d_ws, size_t ws_size,
                              hipStream_t stream) {
  (void)in_sizes; (void)n_in; (void)out_size;
  if (!g_devF || !g_devC || ws_size < WS_TOTAL) return;

  const float* x    = (const float*)d_in[0];
  const float* ks2  = (const float*)d_in[1];
  const float* k1   = (const float*)d_in[2];
  const float* k2   = (const float*)d_in[3];
  const float* k3   = (const float*)d_in[4];
  const float* k4   = (const float*)d_in[5];
  const float* g1   = (const float*)d_in[6],  *be1 = (const float*)d_in[7];
  const float* w1   = (const float*)d_in[8],  *b1  = (const float*)d_in[9];
  const float* g2   = (const float*)d_in[10], *be2 = (const float*)d_in[11];
  const float* w2   = (const float*)d_in[12], *b2  = (const float*)d_in[13];
  const float* g3   = (const float*)d_in[14], *be3 = (const float*)d_in[15];
  const float* w3   = (const float*)d_in[16], *b3  = (const float*)d_in[17];
  float* out = (float*)d_out;
  char* ws = (char*)d_ws;

  float2* XF1 = (float2*)(ws + WS_XF1);
  float2* xh1 = (float2*)(ws + WS_XH1);
  float2* kh1 = (float2*)(ws + WS_KH1);
  float2* yh1 = (float2*)(ws + WS_YH1);
  float2* xt2 = (float2*)(ws + WS_XT2);
  float2* xh2 = (float2*)(ws + WS_XH2);
  float2* kh2 = (float2*)(ws + WS_KH2);
  float2* yh2 = (float2*)(ws + WS_YH2);
  float2* xt3 = (float2*)(ws + WS_XT3);
  float2* xh3 = (float2*)(ws + WS_XH3);
  float2* kh3 = (float2*)(ws + WS_KH3);
  float2* yh3 = (float2*)(ws + WS_YH3);
  float2* xt4 = (float2*)(ws + WS_XT4);
  float2* xh4 = (float2*)(ws + WS_XH4);
  float2* kh4 = (float2*)(ws + WS_KH4);
  float2* yh4 = (float2*)(ws + WS_YH4);
  float2* xt5 = (float2*)(ws + WS_XT5);
  float2* xh5 = (float2*)(ws + WS_XH5);
  float2* kh5 = (float2*)(ws + WS_KH5);
  float2* yh5 = (float2*)(ws + WS_YH5);
  float*  s5p = (float*) (ws + WS_S5P);

  const float* dA1p = g_devF + CO.A1; const float* dA2p = g_devF + CO.A2;
  const float* dA3p = g_devF + CO.A3; const float* dA4p = g_devF + CO.A4;
  const float* dA5p = g_devF + CO.A5;
  const float* dS1p = g_devF + CO.S1; const float* dS2p = g_devF + CO.S2;
  const float* dS3p = g_devF + CO.S3; const float* dS4p = g_devF + CO.S4;
  const float* dS5p = g_devF + CO.S5;
  const float* wIntp = g_devF + CO.WInt;
  const float2* Fs2p  = g_devC + CO.Fs2;
  const float2* Fso3p = g_devC + CO.Fso3;
  const float2* tw60p = g_devC + CO.Tw60; const float2* tw34p = g_devC + CO.Tw34;
  const float2* tw18p = g_devC + CO.Tw18; const float2* tw10p = g_devC + CO.Tw10;
  const float2* tw6p  = g_devC + CO.Tw6;
  const float2* Wn4p = g_devC + CO.Wn4; const float2* Wn5p = g_devC + CO.Wn5;
  const float2* Wg4p = g_devC + CO.Wg4;

  constexpr int Q30 = OQh(30), Q17 = OQh(17), Q9 = OQh(9), Q5 = OQh(5), Q3 = OQh(3);

  // kernel FTs
  k_kh_s2 <<<cdiv_h(1800,256),      256, 0, stream>>>(ks2, Fs2p,  kh1);
  k_kh_so3<<<cdiv_h(Q17*10,256),    256, 0, stream>>>(k1, Fso3p, kh2, 17, 2, 5);
  k_kh_so3<<<cdiv_h(Q9*60,256),     256, 0, stream>>>(k2, Fso3p, kh3, 9, 5, 12);
  k_kh_so3<<<cdiv_h(Q5*336,256),    256, 0, stream>>>(k3, Fso3p, kh4, 5, 12, 28);
  k_kh_so3<<<cdiv_h(Q3*1792,256),   256, 0, stream>>>(k4, Fso3p, kh5, 3, 28, 64);

  // stage 1: s2 analysis + spectral product
  k_s1_fftA<<<32*60, 64, 0, stream>>>(x, tw60p, XF1);
  k_s1_coef<<<cdiv_h(32*900,256), 256, 0, stream>>>(XF1, dA1p, xh1);
  k_s1_yh  <<<cdiv_h(64*Q30,256), 256, 0, stream>>>(xh1, kh1, yh1);

  // stage boundaries: fused synth v3 + coef + yh
  k_synth3<30,60,17,33,256><<<64*60,  256, 0, stream>>>(yh1, dS1p, tw60p, xt2);
  k_coef <<<cdiv_h(64*Q17,256),  256, 0, stream>>>(xt2, dA2p, xh2, 17, 60, 17, 33, Q17, 64);
  k_yh   <<<cdiv_h(160*Q17,256), 256, 0, stream>>>(xh2, kh2, yh2, 17, 2, 5, Q17);

  k_synth3<17,34,9,17,128><<<160*34, 128, 0, stream>>>(yh2, dS2p, tw34p, xt3);
  k_coef <<<cdiv_h(160*Q9,256),  256, 0, stream>>>(xt3, dA3p, xh3, 9, 34, 9, 17, Q9, 160);
  k_yh   <<<cdiv_h(384*Q9,256),  256, 0, stream>>>(xh3, kh3, yh3, 9, 5, 12, Q9);

  k_synth3<9,18,5,9,64><<<384*18, 64, 0, stream>>>(yh3, dS3p, tw18p, xt4);
  k_coef <<<cdiv_h(384*Q5,256),  256, 0, stream>>>(xt4, dA4p, xh4, 5, 18, 5, 9, Q5, 384);
  k_yh   <<<cdiv_h(896*Q5,256),  256, 0, stream>>>(xh4, kh4, yh4, 5, 12, 28, Q5);

  k_synth2<5,10,3,5,0,1,64><<<896*10, 64, 0, stream>>>(yh4, dS4p, tw10p, Wn4p, Wg4p, xt5, nullptr, nullptr);
  k_coef <<<cdiv_h(896*Q3,256),  256, 0, stream>>>(xt5, dA5p, xh5, 3, 10, 3, 5, Q3, 896);
  k_yh   <<<cdiv_h(2048*Q3,256), 256, 0, stream>>>(xh5, kh5, yh5, 3, 28, 64, Q3);

  // final synthesis fused with so3_integrate
  k_synth2<3,6,3,5,1,1,64><<<2048*6, 64, 0, stream>>>(yh5, dS5p, tw6p, Wn5p, nullptr, nullptr, s5p, wIntp);

  // head
  k_mlp<<<1, 256, 0, stream>>>(s5p, g1, be1, w1, b1, g2, be2, w2, b2, g3, be3, w3, b3, out);
}